// Round 1
// baseline (609.599 us; speedup 1.0000x reference)
//
#include <hip/hip_runtime.h>
#include <hip/hip_bf16.h>

typedef unsigned short u16;
typedef unsigned int u32;
typedef __attribute__((ext_vector_type(8))) short bf16x8;
typedef __attribute__((ext_vector_type(4))) float f32x4;

#define DEV __device__ __forceinline__

static constexpr int Bc = 4, Nc = 1024, Dc = 1024, Hc = 16, Mc = 4096, D2c = 2048;

DEV u16 f2bf(float f) {
  u32 u = __builtin_bit_cast(u32, f);
  u = (u + 0x7FFFu + ((u >> 16) & 1u)) >> 16;
  return (u16)u;
}
DEV float bf2f(u16 h) { u32 u = ((u32)h) << 16; return __builtin_bit_cast(float, u); }
DEV void gl_lds16(const void* g, void* l) {
  __builtin_amdgcn_global_load_lds((const __attribute__((address_space(1))) u32*)g,
                                   (__attribute__((address_space(3))) u32*)l, 16, 0, 0);
}

// ---------------- fp32 -> bf16 convert (vectorized) ----------------
__global__ __launch_bounds__(256) void k_f32_to_bf16(const float* __restrict__ in,
                                                     u16* __restrict__ out, int n) {
  int i = (blockIdx.x * 256 + threadIdx.x) * 8;
  if (i >= n) return;
  float4 a = *(const float4*)(in + i);
  float4 b = *(const float4*)(in + i + 4);
  union { u16 s[8]; uint4 v; } r;
  r.s[0] = f2bf(a.x); r.s[1] = f2bf(a.y); r.s[2] = f2bf(a.z); r.s[3] = f2bf(a.w);
  r.s[4] = f2bf(b.x); r.s[5] = f2bf(b.y); r.s[6] = f2bf(b.z); r.s[7] = f2bf(b.w);
  *(uint4*)(out + i) = r.v;
}

// ---------------- fp32 [R][C] -> bf16 [C][R] transpose-convert ----------------
__global__ __launch_bounds__(256) void k_transpose_f32_bf16(const float* __restrict__ in,
                                                            u16* __restrict__ out, int R, int C) {
  __shared__ float t[64][65];
  int c0 = blockIdx.x * 64, r0 = blockIdx.y * 64;
  int tid = threadIdx.x;
  int rr = tid >> 4, cc4 = (tid & 15) * 4;
  for (int k = 0; k < 4; ++k) {
    int r = rr + k * 16;
    float4 v = *(const float4*)(in + (size_t)(r0 + r) * C + c0 + cc4);
    t[r][cc4 + 0] = v.x; t[r][cc4 + 1] = v.y; t[r][cc4 + 2] = v.z; t[r][cc4 + 3] = v.w;
  }
  __syncthreads();
  int cw = tid >> 4, rr4 = (tid & 15) * 4;
  for (int k = 0; k < 4; ++k) {
    int c = cw + k * 16;
    union { u16 s[4]; uint2 v; } p;
    for (int j = 0; j < 4; ++j) p.s[j] = f2bf(t[rr4 + j][c]);
    *(uint2*)(out + (size_t)(c0 + c) * R + r0 + rr4) = p.v;
  }
}

// ---------------- v [B*N, D] -> vt [B*H*64, N] per-head transpose ----------------
__global__ __launch_bounds__(256) void k_v_transpose(const u16* __restrict__ v,
                                                     u16* __restrict__ vt) {
  __shared__ __align__(16) u16 t[64][80];
  int nt = blockIdx.x;
  int bh = blockIdx.y, b = bh >> 4, h = bh & 15;
  int tid = threadIdx.x;
  for (int it = 0; it < 2; ++it) {
    int u = it * 256 + tid; int r = u >> 3, ch = u & 7;
    uint4 raw = *(const uint4*)(v + ((size_t)b * Nc + nt * 64 + r) * Dc + h * 64 + ch * 8);
    *(uint4*)&t[r][ch * 8] = raw;
  }
  __syncthreads();
  for (int it = 0; it < 2; ++it) {
    int u = it * 256 + tid; int d = u >> 3, nch = u & 7;
    union { u16 s[8]; uint4 v4; } p;
    for (int j = 0; j < 8; ++j) p.s[j] = t[nch * 8 + j][d];
    *(uint4*)(vt + ((size_t)bh * 64 + d) * Nc + nt * 64 + nch * 8) = p.v4;
  }
}

// ---------------- GEMM: C[M,N] = (A[M,K] * Bt[N,K]^T + bias) * scale (+resid) ----------------
// A may be split: k < Ksplit -> A1 (lda=Ksplit), else A2 (lda=K-Ksplit).
template <bool OUT_BF16>
__global__ __launch_bounds__(256) void k_gemm(const u16* __restrict__ A1, const u16* __restrict__ A2,
                                              int Ksplit, const u16* __restrict__ Bt,
                                              const float* __restrict__ bias,
                                              const float* __restrict__ resid,
                                              void* __restrict__ out,
                                              int M, int N, int K, float scale) {
  __shared__ __align__(16) u16 As[128 * 64];
  __shared__ __align__(16) u16 Bs[128 * 64];
  int tid = threadIdx.x;
  int w = tid >> 6, l = tid & 63;
  int lo = l & 15, hi = l >> 4;
  int m0 = blockIdx.y * 128, n0 = blockIdx.x * 128;
  f32x4 acc[4][4] = {};
  int wm = (w >> 1) * 64, wn = (w & 1) * 64;

  for (int kt = 0; kt < K; kt += 64) {
    const u16* Ab; int lda, kof;
    if (kt < Ksplit) { Ab = A1; lda = Ksplit; kof = kt; }
    else             { Ab = A2; lda = K - Ksplit; kof = kt - Ksplit; }
#pragma unroll
    for (int i = 0; i < 4; ++i) {
      int ebase = (i * 4 + w) * 512;
      int e = ebase + l * 8;
      int r = e >> 6, s = (e >> 3) & 7;
      gl_lds16(Ab + (size_t)(m0 + r) * lda + kof + 8 * (s ^ (r & 7)), &As[ebase]);
    }
#pragma unroll
    for (int i = 0; i < 4; ++i) {
      int ebase = (i * 4 + w) * 512;
      int e = ebase + l * 8;
      int r = e >> 6, s = (e >> 3) & 7;
      gl_lds16(Bt + (size_t)(n0 + r) * K + kt + 8 * (s ^ (r & 7)), &Bs[ebase]);
    }
    __syncthreads();
#pragma unroll
    for (int kk = 0; kk < 2; ++kk) {
      bf16x8 af[4], bfv[4];
#pragma unroll
      for (int m = 0; m < 4; ++m) {
        int r = wm + m * 16 + lo;
        int slot = (kk * 4 + hi) ^ (r & 7);
        af[m] = *(const bf16x8*)&As[r * 64 + slot * 8];
      }
#pragma unroll
      for (int n = 0; n < 4; ++n) {
        int r = wn + n * 16 + lo;
        int slot = (kk * 4 + hi) ^ (r & 7);
        bfv[n] = *(const bf16x8*)&Bs[r * 64 + slot * 8];
      }
#pragma unroll
      for (int m = 0; m < 4; ++m)
#pragma unroll
        for (int n = 0; n < 4; ++n)
          acc[m][n] = __builtin_amdgcn_mfma_f32_16x16x32_bf16(af[m], bfv[n], acc[m][n], 0, 0, 0);
    }
    __syncthreads();
  }

#pragma unroll
  for (int m = 0; m < 4; ++m)
#pragma unroll
    for (int n = 0; n < 4; ++n) {
      int Cc_ = n0 + wn + n * 16 + lo;
      float bvv = bias ? bias[Cc_] : 0.f;
#pragma unroll
      for (int i = 0; i < 4; ++i) {
        int Rr = m0 + wm + m * 16 + hi * 4 + i;
        float v = (acc[m][n][i] + bvv) * scale;
        if (resid) v += resid[(size_t)Rr * N + Cc_];
        if (OUT_BF16) ((u16*)out)[(size_t)Rr * N + Cc_] = f2bf(v);
        else          ((float*)out)[(size_t)Rr * N + Cc_] = v;
      }
    }
}

// ---------------- flash attention: Out = softmax(Q K^T) V ----------------
// Q,K: bf16 [B*N, D] (head h at cols h*64..), Vt: bf16 [B*H*64, N], Out: bf16 [B*N, D]
__global__ __launch_bounds__(256) void k_attn(const u16* __restrict__ Q, const u16* __restrict__ Kg,
                                              const u16* __restrict__ Vt, u16* __restrict__ Out) {
  __shared__ __align__(16) u16 q_lds[64 * 64];
  __shared__ __align__(16) u16 k_lds[64 * 64];
  __shared__ __align__(16) u16 v_lds[64 * 64];
  __shared__ __align__(16) u16 p_lds[4][16 * 64];
  int tid = threadIdx.x;
  int w = tid >> 6, l = tid & 63;
  int lo = l & 15, hi = l >> 4;
  int qt = blockIdx.x;
  int bh = blockIdx.y, b = bh >> 4, h = bh & 15;
  size_t rowQ0 = (size_t)b * Nc + qt * 64;

#pragma unroll
  for (int i = 0; i < 2; ++i) {
    int ebase = (i * 4 + w) * 512;
    int e = ebase + l * 8;
    int r = e >> 6, s = (e >> 3) & 7;
    gl_lds16(Q + (rowQ0 + r) * Dc + h * 64 + 8 * (s ^ (r & 7)), &q_lds[ebase]);
  }
  __syncthreads();
  bf16x8 qf[2];
#pragma unroll
  for (int c = 0; c < 2; ++c) {
    int r = w * 16 + lo;
    int slot = (c * 4 + hi) ^ (r & 7);
    qf[c] = *(const bf16x8*)&q_lds[r * 64 + slot * 8];
  }

  f32x4 o[4] = {};
  float mx[4], ls[4];
#pragma unroll
  for (int i = 0; i < 4; ++i) { mx[i] = -INFINITY; ls[i] = 0.f; }

  for (int t = 0; t < Nc / 64; ++t) {
#pragma unroll
    for (int i = 0; i < 2; ++i) {
      int ebase = (i * 4 + w) * 512;
      int e = ebase + l * 8;
      int r = e >> 6, s = (e >> 3) & 7;
      gl_lds16(Kg + ((size_t)b * Nc + t * 64 + r) * Dc + h * 64 + 8 * (s ^ (r & 7)), &k_lds[ebase]);
      gl_lds16(Vt + ((size_t)bh * 64 + r) * Nc + t * 64 + 8 * (s ^ (r & 7)), &v_lds[ebase]);
    }
    __syncthreads();

    f32x4 sf[4] = {};
#pragma unroll
    for (int c = 0; c < 2; ++c)
#pragma unroll
      for (int kt = 0; kt < 4; ++kt) {
        int r = kt * 16 + lo;
        int slot = (c * 4 + hi) ^ (r & 7);
        bf16x8 kb = *(const bf16x8*)&k_lds[r * 64 + slot * 8];
        sf[kt] = __builtin_amdgcn_mfma_f32_16x16x32_bf16(qf[c], kb, sf[kt], 0, 0, 0);
      }

    float pv[4][4];
#pragma unroll
    for (int i = 0; i < 4; ++i) {
      float tm = fmaxf(fmaxf(sf[0][i], sf[1][i]), fmaxf(sf[2][i], sf[3][i]));
#pragma unroll
      for (int off = 1; off < 16; off <<= 1) tm = fmaxf(tm, __shfl_xor(tm, off));
      float mn = fmaxf(mx[i], tm);
      float alpha = __expf(mx[i] - mn);
      mx[i] = mn;
      float ps = 0.f;
#pragma unroll
      for (int kt = 0; kt < 4; ++kt) { float p = __expf(sf[kt][i] - mn); pv[kt][i] = p; ps += p; }
#pragma unroll
      for (int off = 1; off < 16; off <<= 1) ps += __shfl_xor(ps, off);
      ls[i] = ls[i] * alpha + ps;
#pragma unroll
      for (int dt = 0; dt < 4; ++dt) o[dt][i] *= alpha;
    }

#pragma unroll
    for (int kt = 0; kt < 4; ++kt)
#pragma unroll
      for (int i = 0; i < 4; ++i) {
        int q = hi * 4 + i, k = kt * 16 + lo;
        int slot = (k >> 3) ^ (q & 7);
        p_lds[w][q * 64 + slot * 8 + (k & 7)] = f2bf(pv[kt][i]);
      }

#pragma unroll
    for (int ks = 0; ks < 2; ++ks) {
      int slotp = (ks * 4 + hi) ^ (lo & 7);
      bf16x8 pa = *(const bf16x8*)&p_lds[w][lo * 64 + slotp * 8];
#pragma unroll
      for (int dt = 0; dt < 4; ++dt) {
        int r = dt * 16 + lo;
        int slot = (ks * 4 + hi) ^ (r & 7);
        bf16x8 vb = *(const bf16x8*)&v_lds[r * 64 + slot * 8];
        o[dt] = __builtin_amdgcn_mfma_f32_16x16x32_bf16(pa, vb, o[dt], 0, 0, 0);
      }
    }
    __syncthreads();
  }

#pragma unroll
  for (int dt = 0; dt < 4; ++dt)
#pragma unroll
    for (int i = 0; i < 4; ++i) {
      int Rr = qt * 64 + w * 16 + hi * 4 + i;
      float v = o[dt][i] / ls[i];
      Out[((size_t)b * Nc + Rr) * Dc + h * 64 + dt * 16 + lo] = f2bf(v);
    }
}

// ---------------- LayerNorm + exact GeLU, in-place on bf16 [rows][2048] ----------------
__global__ __launch_bounds__(256) void k_ln_gelu(u16* __restrict__ hbuf,
                                                 const float* __restrict__ gamma,
                                                 const float* __restrict__ beta) {
  int row = blockIdx.x;
  u16* hp = hbuf + (size_t)row * D2c;
  int tid = threadIdx.x;
  uint4 raw = *(const uint4*)(hp + tid * 8);
  u16* rs = (u16*)&raw;
  float vals[8];
  float s = 0.f, s2 = 0.f;
#pragma unroll
  for (int j = 0; j < 8; ++j) { float v = bf2f(rs[j]); vals[j] = v; s += v; s2 += v * v; }
#pragma unroll
  for (int off = 1; off < 64; off <<= 1) { s += __shfl_xor(s, off); s2 += __shfl_xor(s2, off); }
  __shared__ float red[2][4];
  int w = tid >> 6, l = tid & 63;
  if (l == 0) { red[0][w] = s; red[1][w] = s2; }
  __syncthreads();
  s = red[0][0] + red[0][1] + red[0][2] + red[0][3];
  s2 = red[1][0] + red[1][1] + red[1][2] + red[1][3];
  float mu = s / D2c;
  float var = s2 / D2c - mu * mu;
  float rstd = rsqrtf(var + 1e-5f);
  union { u16 s[8]; uint4 v; } outp;
#pragma unroll
  for (int j = 0; j < 8; ++j) {
    int c = tid * 8 + j;
    float v = (vals[j] - mu) * rstd * gamma[c] + beta[c];
    float g = 0.5f * v * (1.f + erff(v * 0.70710678118654752f));
    outp.s[j] = f2bf(g);
  }
  *(uint4*)(hp + tid * 8) = outp.v;
}

extern "C" void kernel_launch(void* const* d_in, const int* in_sizes, int n_in,
                              void* d_out, int out_size, void* d_ws, size_t ws_size,
                              hipStream_t stream) {
  const float* x0   = (const float*)d_in[0];
  const float* x1   = (const float*)d_in[1];
  const float* Wqk  = (const float*)d_in[2];
  const float* bqk  = (const float*)d_in[3];
  const float* Wv   = (const float*)d_in[4];
  const float* bv   = (const float*)d_in[5];
  const float* Wo   = (const float*)d_in[6];
  const float* bo   = (const float*)d_in[7];
  const float* Wf1  = (const float*)d_in[8];
  const float* bf1  = (const float*)d_in[9];
  const float* gamma= (const float*)d_in[10];
  const float* beta = (const float*)d_in[11];
  const float* Wf2  = (const float*)d_in[12];
  const float* bf2  = (const float*)d_in[13];
  float* y = (float*)d_out;

  char* p = (char*)d_ws;
  auto take = [&](size_t elems) { u16* r = (u16*)p; p += ((elems * 2 + 255) & ~(size_t)255); return r; };
  u16* Wqkt = take((size_t)1024 * 1024);
  u16* Wvt  = take((size_t)1024 * 1024);
  u16* Wot  = take((size_t)1024 * 1024);
  u16* Wf1t = take((size_t)2048 * 2048);
  u16* Wf2t = take((size_t)1024 * 2048);
  u16* x0b  = take((size_t)4096 * 1024);
  u16* x1b  = take((size_t)4096 * 1024);
  u16* h0   = take((size_t)4096 * 2048);  // aliased: qk0 | qk1 before FFN1
  u16* h1   = take((size_t)4096 * 2048);  // aliased: vt0 | vt1 before FFN1
  u16* m0b  = take((size_t)4096 * 1024);  // aliased: v0 (pre-transpose) then attn out 0
  u16* m1b  = take((size_t)4096 * 1024);  // aliased: v1 then attn out 1
  u16* o0b  = take((size_t)4096 * 1024);
  u16* o1b  = take((size_t)4096 * 1024);
  u16* qk0 = h0; u16* qk1 = h0 + (size_t)4096 * 1024;
  u16* vt0 = h1; u16* vt1 = h1 + (size_t)4096 * 1024;

  dim3 blk(256);
  const float sq = 0.3535533905932738f;  // (1/8)^0.5; applied to both qk -> total 1/8

  // weight transposes + input converts
  k_transpose_f32_bf16<<<dim3(16, 16), blk, 0, stream>>>(Wqk, Wqkt, 1024, 1024);
  k_transpose_f32_bf16<<<dim3(16, 16), blk, 0, stream>>>(Wv, Wvt, 1024, 1024);
  k_transpose_f32_bf16<<<dim3(16, 16), blk, 0, stream>>>(Wo, Wot, 1024, 1024);
  k_transpose_f32_bf16<<<dim3(32, 32), blk, 0, stream>>>(Wf1, Wf1t, 2048, 2048);
  k_transpose_f32_bf16<<<dim3(16, 32), blk, 0, stream>>>(Wf2, Wf2t, 2048, 1024);
  k_f32_to_bf16<<<dim3(2048), blk, 0, stream>>>(x0, x0b, 4096 * 1024);
  k_f32_to_bf16<<<dim3(2048), blk, 0, stream>>>(x1, x1b, 4096 * 1024);

  // projections
  k_gemm<true><<<dim3(8, 32), blk, 0, stream>>>(x0b, x0b, 1024, Wqkt, bqk, nullptr, qk0, 4096, 1024, 1024, sq);
  k_gemm<true><<<dim3(8, 32), blk, 0, stream>>>(x1b, x1b, 1024, Wqkt, bqk, nullptr, qk1, 4096, 1024, 1024, sq);
  k_gemm<true><<<dim3(8, 32), blk, 0, stream>>>(x0b, x0b, 1024, Wvt, bv, nullptr, m0b, 4096, 1024, 1024, 1.f);
  k_gemm<true><<<dim3(8, 32), blk, 0, stream>>>(x1b, x1b, 1024, Wvt, bv, nullptr, m1b, 4096, 1024, 1024, 1.f);

  // per-head transposes of V
  k_v_transpose<<<dim3(16, 64), blk, 0, stream>>>(m0b, vt0);
  k_v_transpose<<<dim3(16, 64), blk, 0, stream>>>(m1b, vt1);

  // cross attentions (m0 overwrites v0 buffer, m1 overwrites v1 buffer)
  k_attn<<<dim3(16, 64), blk, 0, stream>>>(qk0, qk1, vt1, m0b);
  k_attn<<<dim3(16, 64), blk, 0, stream>>>(qk1, qk0, vt0, m1b);

  // output projection
  k_gemm<true><<<dim3(8, 32), blk, 0, stream>>>(m0b, m0b, 1024, Wot, bo, nullptr, o0b, 4096, 1024, 1024, 1.f);
  k_gemm<true><<<dim3(8, 32), blk, 0, stream>>>(m1b, m1b, 1024, Wot, bo, nullptr, o1b, 4096, 1024, 1024, 1.f);

  // FFN1 on concat([x, o]) via split-A GEMM (overwrites qk/vt regions, now dead)
  k_gemm<true><<<dim3(16, 32), blk, 0, stream>>>(x0b, o0b, 1024, Wf1t, bf1, nullptr, h0, 4096, 2048, 2048, 1.f);
  k_gemm<true><<<dim3(16, 32), blk, 0, stream>>>(x1b, o1b, 1024, Wf1t, bf1, nullptr, h1, 4096, 2048, 2048, 1.f);

  // LayerNorm + GeLU in place
  k_ln_gelu<<<dim3(4096), blk, 0, stream>>>(h0, gamma, beta);
  k_ln_gelu<<<dim3(4096), blk, 0, stream>>>(h1, gamma, beta);

  // FFN2 + residual -> fp32 outputs
  k_gemm<false><<<dim3(8, 32), blk, 0, stream>>>(h0, h0, 2048, Wf2t, bf2, x0, y, 4096, 1024, 2048, 1.f);
  k_gemm<false><<<dim3(8, 32), blk, 0, stream>>>(h1, h1, 2048, Wf2t, bf2, x1, y + (size_t)4096 * 1024, 4096, 1024, 2048, 1.f);
}

// Round 2
// 463.973 us; speedup vs baseline: 1.3139x; 1.3139x over previous
//
#include <hip/hip_runtime.h>
#include <hip/hip_bf16.h>

typedef unsigned short u16;
typedef unsigned int u32;
typedef __attribute__((ext_vector_type(8))) short bf16x8;
typedef __attribute__((ext_vector_type(4))) float f32x4;

#define DEV __device__ __forceinline__

static constexpr int Bc = 4, Nc = 1024, Dc = 1024, Hc = 16, Mc = 4096, D2c = 2048;
static constexpr size_t VT_STRIDE = (size_t)4 * 16 * 64 * 1024;  // per-stream vt elems

DEV u16 f2bf(float f) {
  u32 u = __builtin_bit_cast(u32, f);
  u = (u + 0x7FFFu + ((u >> 16) & 1u)) >> 16;
  return (u16)u;
}
DEV float bf2f(u16 h) { u32 u = ((u32)h) << 16; return __builtin_bit_cast(float, u); }
DEV void gl_lds16(const void* g, void* l) {
  __builtin_amdgcn_global_load_lds((const __attribute__((address_space(1))) u32*)g,
                                   (__attribute__((address_space(3))) u32*)l, 16, 0, 0);
}

// ---------------- fp32 -> bf16 convert (vectorized) ----------------
__global__ __launch_bounds__(256) void k_f32_to_bf16(const float* __restrict__ in,
                                                     u16* __restrict__ out, int n) {
  int i = (blockIdx.x * 256 + threadIdx.x) * 8;
  if (i >= n) return;
  float4 a = *(const float4*)(in + i);
  float4 b = *(const float4*)(in + i + 4);
  union { u16 s[8]; uint4 v; } r;
  r.s[0] = f2bf(a.x); r.s[1] = f2bf(a.y); r.s[2] = f2bf(a.z); r.s[3] = f2bf(a.w);
  r.s[4] = f2bf(b.x); r.s[5] = f2bf(b.y); r.s[6] = f2bf(b.z); r.s[7] = f2bf(b.w);
  *(uint4*)(out + i) = r.v;
}

// ---------------- fp32 [R][C] -> bf16 [C][R] transpose-convert ----------------
__global__ __launch_bounds__(256) void k_transpose_f32_bf16(const float* __restrict__ in,
                                                            u16* __restrict__ out, int R, int C) {
  __shared__ float t[64][65];
  int c0 = blockIdx.x * 64, r0 = blockIdx.y * 64;
  int tid = threadIdx.x;
  int rr = tid >> 4, cc4 = (tid & 15) * 4;
  for (int k = 0; k < 4; ++k) {
    int r = rr + k * 16;
    float4 v = *(const float4*)(in + (size_t)(r0 + r) * C + c0 + cc4);
    t[r][cc4 + 0] = v.x; t[r][cc4 + 1] = v.y; t[r][cc4 + 2] = v.z; t[r][cc4 + 3] = v.w;
  }
  __syncthreads();
  int cw = tid >> 4, rr4 = (tid & 15) * 4;
  for (int k = 0; k < 4; ++k) {
    int c = cw + k * 16;
    union { u16 s[4]; uint2 v; } p;
    for (int j = 0; j < 4; ++j) p.s[j] = f2bf(t[rr4 + j][c]);
    *(uint2*)(out + (size_t)(c0 + c) * R + r0 + rr4) = p.v;
  }
}

// ---------------- v (cols 1024.. of qkv, stride 2048) -> vt [z][B*H*64, N] ----------------
__global__ __launch_bounds__(256) void k_v_transpose(const u16* __restrict__ qkv,
                                                     u16* __restrict__ vt01) {
  __shared__ __align__(16) u16 t[64][80];
  int z = blockIdx.z;
  const u16* v = qkv + (size_t)z * Mc * 2048 + 1024;
  u16* vt = vt01 + (size_t)z * VT_STRIDE;
  int nt = blockIdx.x;
  int bh = blockIdx.y, b = bh >> 4, h = bh & 15;
  int tid = threadIdx.x;
  for (int it = 0; it < 2; ++it) {
    int u = it * 256 + tid; int r = u >> 3, ch = u & 7;
    uint4 raw = *(const uint4*)(v + ((size_t)b * Nc + nt * 64 + r) * 2048 + h * 64 + ch * 8);
    *(uint4*)&t[r][ch * 8] = raw;
  }
  __syncthreads();
  for (int it = 0; it < 2; ++it) {
    int u = it * 256 + tid; int d = u >> 3, nch = u & 7;
    union { u16 s[8]; uint4 v4; } p;
    for (int j = 0; j < 8; ++j) p.s[j] = t[nch * 8 + j][d];
    *(uint4*)(vt + ((size_t)bh * 64 + d) * Nc + nt * 64 + nch * 8) = p.v4;
  }
}

// ---------------- GEMM: C = (split-A * Bt^T + bias) * scale (+resid) ----------------
template <bool OUT_BF16>
__global__ __launch_bounds__(256) void k_gemm(
    const u16* __restrict__ A1, int lda1, const u16* __restrict__ A2, int lda2, int Ksplit,
    const u16* __restrict__ Bt,
    const float* __restrict__ bias1, const float* __restrict__ bias2, int Nsplit,
    float scale1, float scale2,
    const float* __restrict__ resid0, const float* __restrict__ resid1, int Msplit,
    void* __restrict__ out, int ldc, int K) {
  __shared__ __align__(16) u16 As[128 * 64];
  __shared__ __align__(16) u16 Bs[128 * 64];
  int tid = threadIdx.x;
  int w = tid >> 6, l = tid & 63;
  int lo = l & 15, hi = l >> 4;
  int m0 = blockIdx.y * 128, n0 = blockIdx.x * 128;
  f32x4 acc[4][4] = {};
  int wm = (w >> 1) * 64, wn = (w & 1) * 64;

  for (int kt = 0; kt < K; kt += 64) {
    const u16* Ab; int lda, kof;
    if (kt < Ksplit) { Ab = A1; lda = lda1; kof = kt; }
    else             { Ab = A2; lda = lda2; kof = kt - Ksplit; }
#pragma unroll
    for (int i = 0; i < 4; ++i) {
      int ebase = (i * 4 + w) * 512;
      int e = ebase + l * 8;
      int r = e >> 6, s = (e >> 3) & 7;
      gl_lds16(Ab + (size_t)(m0 + r) * lda + kof + 8 * (s ^ (r & 7)), &As[ebase]);
    }
#pragma unroll
    for (int i = 0; i < 4; ++i) {
      int ebase = (i * 4 + w) * 512;
      int e = ebase + l * 8;
      int r = e >> 6, s = (e >> 3) & 7;
      gl_lds16(Bt + (size_t)(n0 + r) * K + kt + 8 * (s ^ (r & 7)), &Bs[ebase]);
    }
    __syncthreads();
#pragma unroll
    for (int kk = 0; kk < 2; ++kk) {
      bf16x8 af[4], bfv[4];
#pragma unroll
      for (int m = 0; m < 4; ++m) {
        int r = wm + m * 16 + lo;
        int slot = (kk * 4 + hi) ^ (r & 7);
        af[m] = *(const bf16x8*)&As[r * 64 + slot * 8];
      }
#pragma unroll
      for (int n = 0; n < 4; ++n) {
        int r = wn + n * 16 + lo;
        int slot = (kk * 4 + hi) ^ (r & 7);
        bfv[n] = *(const bf16x8*)&Bs[r * 64 + slot * 8];
      }
#pragma unroll
      for (int m = 0; m < 4; ++m)
#pragma unroll
        for (int n = 0; n < 4; ++n)
          acc[m][n] = __builtin_amdgcn_mfma_f32_16x16x32_bf16(af[m], bfv[n], acc[m][n], 0, 0, 0);
    }
    __syncthreads();
  }

  const float* bias = bias1; float scl = scale1; int coff = 0;
  if (bias2 && n0 >= Nsplit) { bias = bias2; scl = scale2; coff = Nsplit; }
  const float* resid = nullptr; int roff = 0;
  if (resid0) { if (m0 < Msplit) { resid = resid0; roff = 0; } else { resid = resid1; roff = Msplit; } }

#pragma unroll
  for (int m = 0; m < 4; ++m)
#pragma unroll
    for (int n = 0; n < 4; ++n) {
      int Cc_ = n0 + wn + n * 16 + lo;
      float bvv = bias ? bias[Cc_ - coff] : 0.f;
#pragma unroll
      for (int i = 0; i < 4; ++i) {
        int Rr = m0 + wm + m * 16 + hi * 4 + i;
        float v = (acc[m][n][i] + bvv) * scl;
        if (resid) v += resid[(size_t)(Rr - roff) * ldc + Cc_];
        if (OUT_BF16) ((u16*)out)[(size_t)Rr * ldc + Cc_] = f2bf(v);
        else          ((float*)out)[(size_t)Rr * ldc + Cc_] = v;
      }
    }
}

// ---------------- flash attention over fused qkv buffer ----------------
// z=0: Q=qk(stream0), K=qk(stream1), V=vt1, Out=m0 ; z=1: swapped.
__global__ __launch_bounds__(256) void k_attn(const u16* __restrict__ qkv,
                                              const u16* __restrict__ vt01,
                                              u16* __restrict__ m01) {
  __shared__ __align__(16) u16 q_lds[64 * 64];
  __shared__ __align__(16) u16 k_lds[64 * 64];
  __shared__ __align__(16) u16 v_lds[64 * 64];
  __shared__ __align__(16) u16 p_lds[4][16 * 64];
  int z = blockIdx.z;
  const u16* Q  = qkv + (size_t)z * Mc * 2048;
  const u16* Kg = qkv + (size_t)(1 - z) * Mc * 2048;
  const u16* Vt = vt01 + (size_t)(1 - z) * VT_STRIDE;
  u16* Out = m01 + (size_t)z * Mc * Dc;
  int tid = threadIdx.x;
  int w = tid >> 6, l = tid & 63;
  int lo = l & 15, hi = l >> 4;
  int qt = blockIdx.x;
  int bh = blockIdx.y, b = bh >> 4, h = bh & 15;
  size_t rowQ0 = (size_t)b * Nc + qt * 64;

#pragma unroll
  for (int i = 0; i < 2; ++i) {
    int ebase = (i * 4 + w) * 512;
    int e = ebase + l * 8;
    int r = e >> 6, s = (e >> 3) & 7;
    gl_lds16(Q + (rowQ0 + r) * 2048 + h * 64 + 8 * (s ^ (r & 7)), &q_lds[ebase]);
  }
  __syncthreads();
  bf16x8 qf[2];
#pragma unroll
  for (int c = 0; c < 2; ++c) {
    int r = w * 16 + lo;
    int slot = (c * 4 + hi) ^ (r & 7);
    qf[c] = *(const bf16x8*)&q_lds[r * 64 + slot * 8];
  }

  f32x4 o[4] = {};
  float mx[4], ls[4];
#pragma unroll
  for (int i = 0; i < 4; ++i) { mx[i] = -INFINITY; ls[i] = 0.f; }

  for (int t = 0; t < Nc / 64; ++t) {
#pragma unroll
    for (int i = 0; i < 2; ++i) {
      int ebase = (i * 4 + w) * 512;
      int e = ebase + l * 8;
      int r = e >> 6, s = (e >> 3) & 7;
      gl_lds16(Kg + ((size_t)b * Nc + t * 64 + r) * 2048 + h * 64 + 8 * (s ^ (r & 7)), &k_lds[ebase]);
      gl_lds16(Vt + ((size_t)bh * 64 + r) * Nc + t * 64 + 8 * (s ^ (r & 7)), &v_lds[ebase]);
    }
    __syncthreads();

    f32x4 sf[4] = {};
#pragma unroll
    for (int c = 0; c < 2; ++c)
#pragma unroll
      for (int kt = 0; kt < 4; ++kt) {
        int r = kt * 16 + lo;
        int slot = (c * 4 + hi) ^ (r & 7);
        bf16x8 kb = *(const bf16x8*)&k_lds[r * 64 + slot * 8];
        sf[kt] = __builtin_amdgcn_mfma_f32_16x16x32_bf16(qf[c], kb, sf[kt], 0, 0, 0);
      }

    float pv[4][4];
#pragma unroll
    for (int i = 0; i < 4; ++i) {
      float tm = fmaxf(fmaxf(sf[0][i], sf[1][i]), fmaxf(sf[2][i], sf[3][i]));
#pragma unroll
      for (int off = 1; off < 16; off <<= 1) tm = fmaxf(tm, __shfl_xor(tm, off));
      float mn = fmaxf(mx[i], tm);
      float alpha = __expf(mx[i] - mn);
      mx[i] = mn;
      float ps = 0.f;
#pragma unroll
      for (int kt = 0; kt < 4; ++kt) { float p = __expf(sf[kt][i] - mn); pv[kt][i] = p; ps += p; }
#pragma unroll
      for (int off = 1; off < 16; off <<= 1) ps += __shfl_xor(ps, off);
      ls[i] = ls[i] * alpha + ps;
#pragma unroll
      for (int dt = 0; dt < 4; ++dt) o[dt][i] *= alpha;
    }

#pragma unroll
    for (int kt = 0; kt < 4; ++kt)
#pragma unroll
      for (int i = 0; i < 4; ++i) {
        int q = hi * 4 + i, k = kt * 16 + lo;
        int slot = (k >> 3) ^ (q & 7);
        p_lds[w][q * 64 + slot * 8 + (k & 7)] = f2bf(pv[kt][i]);
      }

#pragma unroll
    for (int ks = 0; ks < 2; ++ks) {
      int slotp = (ks * 4 + hi) ^ (lo & 7);
      bf16x8 pa = *(const bf16x8*)&p_lds[w][lo * 64 + slotp * 8];
#pragma unroll
      for (int dt = 0; dt < 4; ++dt) {
        int r = dt * 16 + lo;
        int slot = (ks * 4 + hi) ^ (r & 7);
        bf16x8 vb = *(const bf16x8*)&v_lds[r * 64 + slot * 8];
        o[dt] = __builtin_amdgcn_mfma_f32_16x16x32_bf16(pa, vb, o[dt], 0, 0, 0);
      }
    }
    __syncthreads();
  }

#pragma unroll
  for (int dt = 0; dt < 4; ++dt)
#pragma unroll
    for (int i = 0; i < 4; ++i) {
      int Rr = qt * 64 + w * 16 + hi * 4 + i;
      float v = o[dt][i] / ls[i];
      Out[((size_t)b * Nc + Rr) * Dc + h * 64 + dt * 16 + lo] = f2bf(v);
    }
}

// ---------------- LayerNorm + exact GeLU, in-place on bf16 [rows][2048] ----------------
__global__ __launch_bounds__(256) void k_ln_gelu(u16* __restrict__ hbuf,
                                                 const float* __restrict__ gamma,
                                                 const float* __restrict__ beta) {
  int row = blockIdx.x;
  u16* hp = hbuf + (size_t)row * D2c;
  int tid = threadIdx.x;
  uint4 raw = *(const uint4*)(hp + tid * 8);
  u16* rs = (u16*)&raw;
  float vals[8];
  float s = 0.f, s2 = 0.f;
#pragma unroll
  for (int j = 0; j < 8; ++j) { float v = bf2f(rs[j]); vals[j] = v; s += v; s2 += v * v; }
#pragma unroll
  for (int off = 1; off < 64; off <<= 1) { s += __shfl_xor(s, off); s2 += __shfl_xor(s2, off); }
  __shared__ float red[2][4];
  int w = tid >> 6, l = tid & 63;
  if (l == 0) { red[0][w] = s; red[1][w] = s2; }
  __syncthreads();
  s = red[0][0] + red[0][1] + red[0][2] + red[0][3];
  s2 = red[1][0] + red[1][1] + red[1][2] + red[1][3];
  float mu = s / D2c;
  float var = s2 / D2c - mu * mu;
  float rstd = rsqrtf(var + 1e-5f);
  union { u16 s[8]; uint4 v; } outp;
#pragma unroll
  for (int j = 0; j < 8; ++j) {
    int c = tid * 8 + j;
    float v = (vals[j] - mu) * rstd * gamma[c] + beta[c];
    float g = 0.5f * v * (1.f + erff(v * 0.70710678118654752f));
    outp.s[j] = f2bf(g);
  }
  *(uint4*)(hp + tid * 8) = outp.v;
}

extern "C" void kernel_launch(void* const* d_in, const int* in_sizes, int n_in,
                              void* d_out, int out_size, void* d_ws, size_t ws_size,
                              hipStream_t stream) {
  const float* x0   = (const float*)d_in[0];
  const float* x1   = (const float*)d_in[1];
  const float* Wqk  = (const float*)d_in[2];
  const float* bqk  = (const float*)d_in[3];
  const float* Wv   = (const float*)d_in[4];
  const float* bv   = (const float*)d_in[5];
  const float* Wo   = (const float*)d_in[6];
  const float* bo   = (const float*)d_in[7];
  const float* Wf1  = (const float*)d_in[8];
  const float* bf1  = (const float*)d_in[9];
  const float* gamma= (const float*)d_in[10];
  const float* beta = (const float*)d_in[11];
  const float* Wf2  = (const float*)d_in[12];
  const float* bf2  = (const float*)d_in[13];
  float* y = (float*)d_out;

  char* p = (char*)d_ws;
  auto take = [&](size_t elems) { u16* r = (u16*)p; p += ((elems * 2 + 255) & ~(size_t)255); return r; };
  u16* Wqkvt = take((size_t)2048 * 1024);   // rows 0..1023 = Wqk^T, 1024..2047 = Wv^T
  u16* Wot   = take((size_t)1024 * 1024);
  u16* Wf1t  = take((size_t)2048 * 2048);
  u16* Wf2t  = take((size_t)2048 * 1024);
  u16* x01b  = take((size_t)8192 * 1024);
  u16* qkv   = take((size_t)8192 * 2048);   // later aliased as h01
  u16* vt01  = take(2 * VT_STRIDE);         // later aliased as o01
  u16* m01   = take((size_t)8192 * 1024);
  u16* h01 = qkv;   // FFN1 output (qkv dead after attention)
  u16* o01 = vt01;  // O-proj output (vt dead after attention)

  dim3 blk(256);
  const float sq = 0.3535533905932738f;  // (1/8)^0.5 applied to both qk -> total 1/8

  // weight transposes + input converts
  k_transpose_f32_bf16<<<dim3(16, 16), blk, 0, stream>>>(Wqk, Wqkvt, 1024, 1024);
  k_transpose_f32_bf16<<<dim3(16, 16), blk, 0, stream>>>(Wv, Wqkvt + (size_t)1024 * 1024, 1024, 1024);
  k_transpose_f32_bf16<<<dim3(16, 16), blk, 0, stream>>>(Wo, Wot, 1024, 1024);
  k_transpose_f32_bf16<<<dim3(32, 32), blk, 0, stream>>>(Wf1, Wf1t, 2048, 2048);
  k_transpose_f32_bf16<<<dim3(16, 32), blk, 0, stream>>>(Wf2, Wf2t, 2048, 1024);
  k_f32_to_bf16<<<dim3(2048), blk, 0, stream>>>(x0, x01b, 4096 * 1024);
  k_f32_to_bf16<<<dim3(2048), blk, 0, stream>>>(x1, x01b + (size_t)4096 * 1024, 4096 * 1024);

  // fused qk+v projection: [8192,1024] x [1024,2048] -> qkv [8192,2048]
  k_gemm<true><<<dim3(16, 64), blk, 0, stream>>>(
      x01b, 1024, x01b, 1024, 1024, Wqkvt,
      bqk, bv, 1024, sq, 1.f, nullptr, nullptr, 0, qkv, 2048, 1024);

  // per-head V transpose (both streams)
  k_v_transpose<<<dim3(16, 64, 2), blk, 0, stream>>>(qkv, vt01);

  // cross attention (both directions in one dispatch)
  k_attn<<<dim3(16, 64, 2), blk, 0, stream>>>(qkv, vt01, m01);

  // output projection: [8192,1024] x [1024,1024] -> o01
  k_gemm<true><<<dim3(8, 64), blk, 0, stream>>>(
      m01, 1024, m01, 1024, 1024, Wot,
      bo, nullptr, 1024, 1.f, 1.f, nullptr, nullptr, 0, o01, 1024, 1024);

  // FFN1 on concat([x, o]): [8192,2048] x [2048,2048] -> h01
  k_gemm<true><<<dim3(16, 64), blk, 0, stream>>>(
      x01b, 1024, o01, 1024, 1024, Wf1t,
      bf1, nullptr, 2048, 1.f, 1.f, nullptr, nullptr, 0, h01, 2048, 2048);

  // LayerNorm + GeLU in place
  k_ln_gelu<<<dim3(8192), blk, 0, stream>>>(h01, gamma, beta);

  // FFN2 + residual -> fp32 outputs (y0 rows 0..4095, y1 rows 4096..8191)
  k_gemm<false><<<dim3(8, 64), blk, 0, stream>>>(
      h01, 2048, h01, 2048, 2048, Wf2t,
      bf2, nullptr, 1024, 1.f, 1.f, x0, x1, 4096, y, 1024, 2048);
}

// Round 3
// 437.817 us; speedup vs baseline: 1.3924x; 1.0597x over previous
//
#include <hip/hip_runtime.h>
#include <hip/hip_bf16.h>

typedef unsigned short u16;
typedef unsigned int u32;
typedef __attribute__((ext_vector_type(8))) short bf16x8;
typedef __attribute__((ext_vector_type(4))) float f32x4;

#define DEV __device__ __forceinline__

static constexpr int Bc = 4, Nc = 1024, Dc = 1024, Hc = 16, Mc = 4096, D2c = 2048;
static constexpr size_t VT_STRIDE = (size_t)4 * 16 * 64 * 1024;  // per-stream vt elems

DEV u16 f2bf(float f) {
  u32 u = __builtin_bit_cast(u32, f);
  u = (u + 0x7FFFu + ((u >> 16) & 1u)) >> 16;
  return (u16)u;
}
DEV float bf2f(u16 h) { u32 u = ((u32)h) << 16; return __builtin_bit_cast(float, u); }
DEV void gl_lds16(const void* g, void* l) {
  __builtin_amdgcn_global_load_lds((const __attribute__((address_space(1))) u32*)g,
                                   (__attribute__((address_space(3))) u32*)l, 16, 0, 0);
}

// ---------------- fp32 -> bf16 convert (vectorized) ----------------
__global__ __launch_bounds__(256) void k_f32_to_bf16(const float* __restrict__ in,
                                                     u16* __restrict__ out, int n) {
  int i = (blockIdx.x * 256 + threadIdx.x) * 8;
  if (i >= n) return;
  float4 a = *(const float4*)(in + i);
  float4 b = *(const float4*)(in + i + 4);
  union { u16 s[8]; uint4 v; } r;
  r.s[0] = f2bf(a.x); r.s[1] = f2bf(a.y); r.s[2] = f2bf(a.z); r.s[3] = f2bf(a.w);
  r.s[4] = f2bf(b.x); r.s[5] = f2bf(b.y); r.s[6] = f2bf(b.z); r.s[7] = f2bf(b.w);
  *(uint4*)(out + i) = r.v;
}

// ---------------- fp32 [R][C] -> bf16 [C][R] transpose-convert ----------------
__global__ __launch_bounds__(256) void k_transpose_f32_bf16(const float* __restrict__ in,
                                                            u16* __restrict__ out, int R, int C) {
  __shared__ float t[64][65];
  int c0 = blockIdx.x * 64, r0 = blockIdx.y * 64;
  int tid = threadIdx.x;
  int rr = tid >> 4, cc4 = (tid & 15) * 4;
  for (int k = 0; k < 4; ++k) {
    int r = rr + k * 16;
    float4 v = *(const float4*)(in + (size_t)(r0 + r) * C + c0 + cc4);
    t[r][cc4 + 0] = v.x; t[r][cc4 + 1] = v.y; t[r][cc4 + 2] = v.z; t[r][cc4 + 3] = v.w;
  }
  __syncthreads();
  int cw = tid >> 4, rr4 = (tid & 15) * 4;
  for (int k = 0; k < 4; ++k) {
    int c = cw + k * 16;
    union { u16 s[4]; uint2 v; } p;
    for (int j = 0; j < 4; ++j) p.s[j] = f2bf(t[rr4 + j][c]);
    *(uint2*)(out + (size_t)(c0 + c) * R + r0 + rr4) = p.v;
  }
}

// ---------------- v (cols 1024.. of qkv, stride 2048) -> vt [z][B*H*64, N] ----------------
__global__ __launch_bounds__(256) void k_v_transpose(const u16* __restrict__ qkv,
                                                     u16* __restrict__ vt01) {
  __shared__ __align__(16) u16 t[64][80];
  int z = blockIdx.z;
  const u16* v = qkv + (size_t)z * Mc * 2048 + 1024;
  u16* vt = vt01 + (size_t)z * VT_STRIDE;
  int nt = blockIdx.x;
  int bh = blockIdx.y, b = bh >> 4, h = bh & 15;
  int tid = threadIdx.x;
  for (int it = 0; it < 2; ++it) {
    int u = it * 256 + tid; int r = u >> 3, ch = u & 7;
    uint4 raw = *(const uint4*)(v + ((size_t)b * Nc + nt * 64 + r) * 2048 + h * 64 + ch * 8);
    *(uint4*)&t[r][ch * 8] = raw;
  }
  __syncthreads();
  for (int it = 0; it < 2; ++it) {
    int u = it * 256 + tid; int d = u >> 3, nch = u & 7;
    union { u16 s[8]; uint4 v4; } p;
    for (int j = 0; j < 8; ++j) p.s[j] = t[nch * 8 + j][d];
    *(uint4*)(vt + ((size_t)bh * 64 + d) * Nc + nt * 64 + nch * 8) = p.v4;
  }
}

// ---------------- GEMM: C = (split-A * Bt^T + bias) * scale (+resid) ----------------
template <bool OUT_BF16>
__global__ __launch_bounds__(256) void k_gemm(
    const u16* __restrict__ A1, int lda1, const u16* __restrict__ A2, int lda2, int Ksplit,
    const u16* __restrict__ Bt,
    const float* __restrict__ bias1, const float* __restrict__ bias2, int Nsplit,
    float scale1, float scale2,
    const float* __restrict__ resid0, const float* __restrict__ resid1, int Msplit,
    void* __restrict__ out, int ldc, int K) {
  __shared__ __align__(16) u16 As[128 * 64];
  __shared__ __align__(16) u16 Bs[128 * 64];
  int tid = threadIdx.x;
  int w = tid >> 6, l = tid & 63;
  int lo = l & 15, hi = l >> 4;
  int m0 = blockIdx.y * 128, n0 = blockIdx.x * 128;
  f32x4 acc[4][4] = {};
  int wm = (w >> 1) * 64, wn = (w & 1) * 64;

  for (int kt = 0; kt < K; kt += 64) {
    const u16* Ab; int lda, kof;
    if (kt < Ksplit) { Ab = A1; lda = lda1; kof = kt; }
    else             { Ab = A2; lda = lda2; kof = kt - Ksplit; }
#pragma unroll
    for (int i = 0; i < 4; ++i) {
      int ebase = (i * 4 + w) * 512;
      int e = ebase + l * 8;
      int r = e >> 6, s = (e >> 3) & 7;
      gl_lds16(Ab + (size_t)(m0 + r) * lda + kof + 8 * (s ^ (r & 7)), &As[ebase]);
    }
#pragma unroll
    for (int i = 0; i < 4; ++i) {
      int ebase = (i * 4 + w) * 512;
      int e = ebase + l * 8;
      int r = e >> 6, s = (e >> 3) & 7;
      gl_lds16(Bt + (size_t)(n0 + r) * K + kt + 8 * (s ^ (r & 7)), &Bs[ebase]);
    }
    __syncthreads();
#pragma unroll
    for (int kk = 0; kk < 2; ++kk) {
      bf16x8 af[4], bfv[4];
#pragma unroll
      for (int m = 0; m < 4; ++m) {
        int r = wm + m * 16 + lo;
        int slot = (kk * 4 + hi) ^ (r & 7);
        af[m] = *(const bf16x8*)&As[r * 64 + slot * 8];
      }
#pragma unroll
      for (int n = 0; n < 4; ++n) {
        int r = wn + n * 16 + lo;
        int slot = (kk * 4 + hi) ^ (r & 7);
        bfv[n] = *(const bf16x8*)&Bs[r * 64 + slot * 8];
      }
#pragma unroll
      for (int m = 0; m < 4; ++m)
#pragma unroll
        for (int n = 0; n < 4; ++n)
          acc[m][n] = __builtin_amdgcn_mfma_f32_16x16x32_bf16(af[m], bfv[n], acc[m][n], 0, 0, 0);
    }
    __syncthreads();
  }

  const float* bias = bias1; float scl = scale1; int coff = 0;
  if (bias2 && n0 >= Nsplit) { bias = bias2; scl = scale2; coff = Nsplit; }
  const float* resid = nullptr; int roff = 0;
  if (resid0) { if (m0 < Msplit) { resid = resid0; roff = 0; } else { resid = resid1; roff = Msplit; } }

#pragma unroll
  for (int m = 0; m < 4; ++m)
#pragma unroll
    for (int n = 0; n < 4; ++n) {
      int Cc_ = n0 + wn + n * 16 + lo;
      float bvv = bias ? bias[Cc_ - coff] : 0.f;
#pragma unroll
      for (int i = 0; i < 4; ++i) {
        int Rr = m0 + wm + m * 16 + hi * 4 + i;
        float v = (acc[m][n][i] + bvv) * scl;
        if (resid) v += resid[(size_t)(Rr - roff) * ldc + Cc_];
        if (OUT_BF16) ((u16*)out)[(size_t)Rr * ldc + Cc_] = f2bf(v);
        else          ((float*)out)[(size_t)Rr * ldc + Cc_] = v;
      }
    }
}

// ---------------- flash attention (swapped-QK^T, in-register softmax) ----------------
// z=0: Q=qk(stream0), K=qk(stream1), V=vt1, Out=m0 ; z=1: swapped.
// qk is pre-scaled by sqrt(log2e/8) on both sides -> softmax in exp2 domain.
__global__ __launch_bounds__(256) void k_attn(const u16* __restrict__ qkv,
                                              const u16* __restrict__ vt01,
                                              u16* __restrict__ m01) {
  __shared__ __align__(16) u16 q_lds[64 * 64];
  __shared__ __align__(16) u16 k_lds[2][64 * 64];
  __shared__ __align__(16) u16 v_lds[2][64 * 64];
  __shared__ __align__(16) u16 p_lds[4][16 * 64];
  int z = blockIdx.z;
  const u16* Q  = qkv + (size_t)z * Mc * 2048;
  const u16* Kg = qkv + (size_t)(1 - z) * Mc * 2048;
  const u16* Vt = vt01 + (size_t)(1 - z) * VT_STRIDE;
  u16* Out = m01 + (size_t)z * Mc * Dc;
  int tid = threadIdx.x;
  int w = tid >> 6, l = tid & 63;
  int lo = l & 15, hi = l >> 4;
  int qt = blockIdx.x;
  int bh = blockIdx.y, b = bh >> 4, h = bh & 15;
  size_t rowQ0 = (size_t)b * Nc + qt * 64;

  // prologue: stage Q and K/V tile 0
#pragma unroll
  for (int i = 0; i < 2; ++i) {
    int ebase = (i * 4 + w) * 512;
    int e = ebase + l * 8;
    int r = e >> 6, s = (e >> 3) & 7;
    gl_lds16(Q + (rowQ0 + r) * 2048 + h * 64 + 8 * (s ^ (r & 7)), &q_lds[ebase]);
    gl_lds16(Kg + ((size_t)b * Nc + r) * 2048 + h * 64 + 8 * (s ^ (r & 7)), &k_lds[0][ebase]);
    gl_lds16(Vt + ((size_t)bh * 64 + r) * Nc + 8 * (s ^ (r & 7)), &v_lds[0][ebase]);
  }
  __syncthreads();
  bf16x8 qf[2];
#pragma unroll
  for (int c = 0; c < 2; ++c) {
    int r = w * 16 + lo;
    int slot = (c * 4 + hi) ^ (r & 7);
    qf[c] = *(const bf16x8*)&q_lds[r * 64 + slot * 8];
  }

  f32x4 o[4] = {};
  float m_ = -INFINITY, ls = 0.f;
  int cur = 0;

  for (int t = 0; t < Nc / 64; ++t) {
    // async-stage next K/V tile into the other buffer (overlaps this tile's compute)
    if (t + 1 < Nc / 64) {
#pragma unroll
      for (int i = 0; i < 2; ++i) {
        int ebase = (i * 4 + w) * 512;
        int e = ebase + l * 8;
        int r = e >> 6, s = (e >> 3) & 7;
        gl_lds16(Kg + ((size_t)b * Nc + (t + 1) * 64 + r) * 2048 + h * 64 + 8 * (s ^ (r & 7)),
                 &k_lds[cur ^ 1][ebase]);
        gl_lds16(Vt + ((size_t)bh * 64 + r) * Nc + (t + 1) * 64 + 8 * (s ^ (r & 7)),
                 &v_lds[cur ^ 1][ebase]);
      }
    }

    // QK^T swapped: sf[kt][i] = S[k = t*64+kt*16+hi*4+i][q = lo]
    f32x4 sf[4] = {};
    __builtin_amdgcn_s_setprio(1);
#pragma unroll
    for (int c = 0; c < 2; ++c)
#pragma unroll
      for (int kt = 0; kt < 4; ++kt) {
        int r = kt * 16 + lo;
        int slot = (c * 4 + hi) ^ (r & 7);
        bf16x8 kb = *(const bf16x8*)&k_lds[cur][r * 64 + slot * 8];
        sf[kt] = __builtin_amdgcn_mfma_f32_16x16x32_bf16(kb, qf[c], sf[kt], 0, 0, 0);
      }
    __builtin_amdgcn_s_setprio(0);

    // row max (q = lo): 16 in-register values + 2 cross-lane hops
    float tm = sf[0][0];
#pragma unroll
    for (int kt = 0; kt < 4; ++kt)
#pragma unroll
      for (int i = 0; i < 4; ++i) tm = fmaxf(tm, sf[kt][i]);
    tm = fmaxf(tm, __shfl_xor(tm, 16));
    tm = fmaxf(tm, __shfl_xor(tm, 32));

    bool defer = __all(tm <= m_ + 8.0f);
    float mn = defer ? m_ : fmaxf(m_, tm);

    float ps = 0.f;
#pragma unroll
    for (int kt = 0; kt < 4; ++kt)
#pragma unroll
      for (int i = 0; i < 4; ++i) {
        float pp = exp2f(sf[kt][i] - mn);
        sf[kt][i] = pp;
        ps += pp;
      }
    ps += __shfl_xor(ps, 16);
    ps += __shfl_xor(ps, 32);

    if (defer) {
      ls += ps;
    } else {
      float alpha = exp2f(m_ - mn);
      ls = ls * alpha + ps;
      m_ = mn;
      float a0 = __shfl(alpha, hi * 4 + 0);
      float a1 = __shfl(alpha, hi * 4 + 1);
      float a2 = __shfl(alpha, hi * 4 + 2);
      float a3 = __shfl(alpha, hi * 4 + 3);
#pragma unroll
      for (int dt = 0; dt < 4; ++dt) {
        o[dt][0] *= a0; o[dt][1] *= a1; o[dt][2] *= a2; o[dt][3] *= a3;
      }
    }

    // pack P pairs to bf16 and store (swizzled) to per-wave p_lds
#pragma unroll
    for (int kt = 0; kt < 4; ++kt)
#pragma unroll
      for (int i2 = 0; i2 < 4; i2 += 2) {
        u32 pk;
        asm("v_cvt_pk_bf16_f32 %0, %1, %2" : "=v"(pk) : "v"(sf[kt][i2]), "v"(sf[kt][i2 + 1]));
        int k = kt * 16 + hi * 4 + i2;
        int byte = ((((k >> 3) ^ (lo & 7)) << 4) | ((hi & 1) << 3) | (i2 << 1));
        *(u32*)((char*)&p_lds[w][0] + lo * 128 + byte) = pk;
      }

    // PV
    __builtin_amdgcn_s_setprio(1);
#pragma unroll
    for (int ks = 0; ks < 2; ++ks) {
      int slotp = (ks * 4 + hi) ^ (lo & 7);
      bf16x8 pa = *(const bf16x8*)&p_lds[w][lo * 64 + slotp * 8];
#pragma unroll
      for (int dt = 0; dt < 4; ++dt) {
        int r = dt * 16 + lo;
        int slot = (ks * 4 + hi) ^ (r & 7);
        bf16x8 vb = *(const bf16x8*)&v_lds[cur][r * 64 + slot * 8];
        o[dt] = __builtin_amdgcn_mfma_f32_16x16x32_bf16(pa, vb, o[dt], 0, 0, 0);
      }
    }
    __builtin_amdgcn_s_setprio(0);

    __syncthreads();  // drains next-tile stage loads + all waves done with k/v_lds[cur]
    cur ^= 1;
  }

  float i0 = 1.f / __shfl(ls, hi * 4 + 0);
  float i1 = 1.f / __shfl(ls, hi * 4 + 1);
  float i2 = 1.f / __shfl(ls, hi * 4 + 2);
  float i3 = 1.f / __shfl(ls, hi * 4 + 3);
#pragma unroll
  for (int dt = 0; dt < 4; ++dt) {
    int Rr = qt * 64 + w * 16 + hi * 4;
    Out[((size_t)b * Nc + Rr + 0) * Dc + h * 64 + dt * 16 + lo] = f2bf(o[dt][0] * i0);
    Out[((size_t)b * Nc + Rr + 1) * Dc + h * 64 + dt * 16 + lo] = f2bf(o[dt][1] * i1);
    Out[((size_t)b * Nc + Rr + 2) * Dc + h * 64 + dt * 16 + lo] = f2bf(o[dt][2] * i2);
    Out[((size_t)b * Nc + Rr + 3) * Dc + h * 64 + dt * 16 + lo] = f2bf(o[dt][3] * i3);
  }
}

// ---------------- LayerNorm + exact GeLU, in-place on bf16 [rows][2048] ----------------
__global__ __launch_bounds__(256) void k_ln_gelu(u16* __restrict__ hbuf,
                                                 const float* __restrict__ gamma,
                                                 const float* __restrict__ beta) {
  int row = blockIdx.x;
  u16* hp = hbuf + (size_t)row * D2c;
  int tid = threadIdx.x;
  uint4 raw = *(const uint4*)(hp + tid * 8);
  u16* rs = (u16*)&raw;
  float vals[8];
  float s = 0.f, s2 = 0.f;
#pragma unroll
  for (int j = 0; j < 8; ++j) { float v = bf2f(rs[j]); vals[j] = v; s += v; s2 += v * v; }
#pragma unroll
  for (int off = 1; off < 64; off <<= 1) { s += __shfl_xor(s, off); s2 += __shfl_xor(s2, off); }
  __shared__ float red[2][4];
  int w = tid >> 6, l = tid & 63;
  if (l == 0) { red[0][w] = s; red[1][w] = s2; }
  __syncthreads();
  s = red[0][0] + red[0][1] + red[0][2] + red[0][3];
  s2 = red[1][0] + red[1][1] + red[1][2] + red[1][3];
  float mu = s / D2c;
  float var = s2 / D2c - mu * mu;
  float rstd = rsqrtf(var + 1e-5f);
  union { u16 s[8]; uint4 v; } outp;
#pragma unroll
  for (int j = 0; j < 8; ++j) {
    int c = tid * 8 + j;
    float v = (vals[j] - mu) * rstd * gamma[c] + beta[c];
    float g = 0.5f * v * (1.f + erff(v * 0.70710678118654752f));
    outp.s[j] = f2bf(g);
  }
  *(uint4*)(hp + tid * 8) = outp.v;
}

extern "C" void kernel_launch(void* const* d_in, const int* in_sizes, int n_in,
                              void* d_out, int out_size, void* d_ws, size_t ws_size,
                              hipStream_t stream) {
  const float* x0   = (const float*)d_in[0];
  const float* x1   = (const float*)d_in[1];
  const float* Wqk  = (const float*)d_in[2];
  const float* bqk  = (const float*)d_in[3];
  const float* Wv   = (const float*)d_in[4];
  const float* bv   = (const float*)d_in[5];
  const float* Wo   = (const float*)d_in[6];
  const float* bo   = (const float*)d_in[7];
  const float* Wf1  = (const float*)d_in[8];
  const float* bf1  = (const float*)d_in[9];
  const float* gamma= (const float*)d_in[10];
  const float* beta = (const float*)d_in[11];
  const float* Wf2  = (const float*)d_in[12];
  const float* bf2  = (const float*)d_in[13];
  float* y = (float*)d_out;

  char* p = (char*)d_ws;
  auto take = [&](size_t elems) { u16* r = (u16*)p; p += ((elems * 2 + 255) & ~(size_t)255); return r; };
  u16* Wqkvt = take((size_t)2048 * 1024);   // rows 0..1023 = Wqk^T, 1024..2047 = Wv^T
  u16* Wot   = take((size_t)1024 * 1024);
  u16* Wf1t  = take((size_t)2048 * 2048);
  u16* Wf2t  = take((size_t)2048 * 1024);
  u16* x01b  = take((size_t)8192 * 1024);
  u16* qkv   = take((size_t)8192 * 2048);   // later aliased as h01
  u16* vt01  = take(2 * VT_STRIDE);         // later aliased as o01
  u16* m01   = take((size_t)8192 * 1024);
  u16* h01 = qkv;   // FFN1 output (qkv dead after attention)
  u16* o01 = vt01;  // O-proj output (vt dead after attention)

  dim3 blk(256);
  // sqrt(log2(e)/8): applied to both q and k -> S is scaled by log2(e)/8 (exp2-domain softmax)
  const float sq = 0.4246608984f;

  // weight transposes + input converts
  k_transpose_f32_bf16<<<dim3(16, 16), blk, 0, stream>>>(Wqk, Wqkvt, 1024, 1024);
  k_transpose_f32_bf16<<<dim3(16, 16), blk, 0, stream>>>(Wv, Wqkvt + (size_t)1024 * 1024, 1024, 1024);
  k_transpose_f32_bf16<<<dim3(16, 16), blk, 0, stream>>>(Wo, Wot, 1024, 1024);
  k_transpose_f32_bf16<<<dim3(32, 32), blk, 0, stream>>>(Wf1, Wf1t, 2048, 2048);
  k_transpose_f32_bf16<<<dim3(16, 32), blk, 0, stream>>>(Wf2, Wf2t, 2048, 1024);
  k_f32_to_bf16<<<dim3(2048), blk, 0, stream>>>(x0, x01b, 4096 * 1024);
  k_f32_to_bf16<<<dim3(2048), blk, 0, stream>>>(x1, x01b + (size_t)4096 * 1024, 4096 * 1024);

  // fused qk+v projection: [8192,1024] x [1024,2048] -> qkv [8192,2048]
  k_gemm<true><<<dim3(16, 64), blk, 0, stream>>>(
      x01b, 1024, x01b, 1024, 1024, Wqkvt,
      bqk, bv, 1024, sq, 1.f, nullptr, nullptr, 0, qkv, 2048, 1024);

  // per-head V transpose (both streams)
  k_v_transpose<<<dim3(16, 64, 2), blk, 0, stream>>>(qkv, vt01);

  // cross attention (both directions in one dispatch)
  k_attn<<<dim3(16, 64, 2), blk, 0, stream>>>(qkv, vt01, m01);

  // output projection: [8192,1024] x [1024,1024] -> o01
  k_gemm<true><<<dim3(8, 64), blk, 0, stream>>>(
      m01, 1024, m01, 1024, 1024, Wot,
      bo, nullptr, 1024, 1.f, 1.f, nullptr, nullptr, 0, o01, 1024, 1024);

  // FFN1 on concat([x, o]): [8192,2048] x [2048,2048] -> h01
  k_gemm<true><<<dim3(16, 64), blk, 0, stream>>>(
      x01b, 1024, o01, 1024, 1024, Wf1t,
      bf1, nullptr, 2048, 1.f, 1.f, nullptr, nullptr, 0, h01, 2048, 2048);

  // LayerNorm + GeLU in place
  k_ln_gelu<<<dim3(8192), blk, 0, stream>>>(h01, gamma, beta);

  // FFN2 + residual -> fp32 outputs (y0 rows 0..4095, y1 rows 4096..8191)
  k_gemm<false><<<dim3(8, 64), blk, 0, stream>>>(
      h01, 2048, h01, 2048, 2048, Wf2t,
      bf2, nullptr, 1024, 1.f, 1.f, x0, x1, 4096, y, 1024, 2048);
}

// Round 4
// 381.046 us; speedup vs baseline: 1.5998x; 1.1490x over previous
//
#include <hip/hip_runtime.h>
#include <hip/hip_bf16.h>

typedef unsigned short u16;
typedef unsigned int u32;
typedef __attribute__((ext_vector_type(8))) short bf16x8;
typedef __attribute__((ext_vector_type(4))) float f32x4;

#define DEV __device__ __forceinline__
#define FENCE asm volatile("" ::: "memory")
#define WAITL asm volatile("s_waitcnt lgkmcnt(0)" ::: "memory")
#define BAR __builtin_amdgcn_s_barrier()

static constexpr int Bc = 4, Nc = 1024, Dc = 1024, Hc = 16, Mc = 4096, D2c = 2048;
static constexpr size_t VT_STRIDE = (size_t)4 * 16 * 64 * 1024;  // per-stream vt elems

DEV u16 f2bf(float f) {
  u32 u = __builtin_bit_cast(u32, f);
  u = (u + 0x7FFFu + ((u >> 16) & 1u)) >> 16;
  return (u16)u;
}
DEV float bf2f(u16 h) { u32 u = ((u32)h) << 16; return __builtin_bit_cast(float, u); }
DEV void gl_lds16(const void* g, void* l) {
  __builtin_amdgcn_global_load_lds((const __attribute__((address_space(1))) u32*)g,
                                   (__attribute__((address_space(3))) u32*)l, 16, 0, 0);
}

// ---------------- fp32 -> bf16 convert (vectorized) ----------------
__global__ __launch_bounds__(256) void k_f32_to_bf16(const float* __restrict__ in,
                                                     u16* __restrict__ out, int n) {
  int i = (blockIdx.x * 256 + threadIdx.x) * 8;
  if (i >= n) return;
  float4 a = *(const float4*)(in + i);
  float4 b = *(const float4*)(in + i + 4);
  union { u16 s[8]; uint4 v; } r;
  r.s[0] = f2bf(a.x); r.s[1] = f2bf(a.y); r.s[2] = f2bf(a.z); r.s[3] = f2bf(a.w);
  r.s[4] = f2bf(b.x); r.s[5] = f2bf(b.y); r.s[6] = f2bf(b.z); r.s[7] = f2bf(b.w);
  *(uint4*)(out + i) = r.v;
}

// ---------------- fp32 [R][C] -> bf16 [C][R] transpose-convert ----------------
__global__ __launch_bounds__(256) void k_transpose_f32_bf16(const float* __restrict__ in,
                                                            u16* __restrict__ out, int R, int C) {
  __shared__ float t[64][65];
  int c0 = blockIdx.x * 64, r0 = blockIdx.y * 64;
  int tid = threadIdx.x;
  int rr = tid >> 4, cc4 = (tid & 15) * 4;
  for (int k = 0; k < 4; ++k) {
    int r = rr + k * 16;
    float4 v = *(const float4*)(in + (size_t)(r0 + r) * C + c0 + cc4);
    t[r][cc4 + 0] = v.x; t[r][cc4 + 1] = v.y; t[r][cc4 + 2] = v.z; t[r][cc4 + 3] = v.w;
  }
  __syncthreads();
  int cw = tid >> 4, rr4 = (tid & 15) * 4;
  for (int k = 0; k < 4; ++k) {
    int c = cw + k * 16;
    union { u16 s[4]; uint2 v; } p;
    for (int j = 0; j < 4; ++j) p.s[j] = f2bf(t[rr4 + j][c]);
    *(uint2*)(out + (size_t)(c0 + c) * R + r0 + rr4) = p.v;
  }
}

// ---------------- v (cols 1024.. of qkv, stride 2048) -> vt [z][B*H*64, N] ----------------
__global__ __launch_bounds__(256) void k_v_transpose(const u16* __restrict__ qkv,
                                                     u16* __restrict__ vt01) {
  __shared__ __align__(16) u16 t[64][80];
  int z = blockIdx.z;
  const u16* v = qkv + (size_t)z * Mc * 2048 + 1024;
  u16* vt = vt01 + (size_t)z * VT_STRIDE;
  int nt = blockIdx.x;
  int bh = blockIdx.y, b = bh >> 4, h = bh & 15;
  int tid = threadIdx.x;
  for (int it = 0; it < 2; ++it) {
    int u = it * 256 + tid; int r = u >> 3, ch = u & 7;
    uint4 raw = *(const uint4*)(v + ((size_t)b * Nc + nt * 64 + r) * 2048 + h * 64 + ch * 8);
    *(uint4*)&t[r][ch * 8] = raw;
  }
  __syncthreads();
  for (int it = 0; it < 2; ++it) {
    int u = it * 256 + tid; int d = u >> 3, nch = u & 7;
    union { u16 s[8]; uint4 v4; } p;
    for (int j = 0; j < 8; ++j) p.s[j] = t[nch * 8 + j][d];
    *(uint4*)(vt + ((size_t)bh * 64 + d) * Nc + nt * 64 + nch * 8) = p.v4;
  }
}

// ---------------- 256x256x64 8-phase GEMM (T2+T3+T4+T5), bf16 out ----------------
// C[M,N] = (splitA * Bt^T + bias) * scale. 512 threads = 8 waves (2M x 4N),
// per-wave 128x64 output, phases = block C-quadrants (128x128) gray-ordered.
// LDS 128 KiB: A/B x 2 bufs x 2 halves x [128][64] bf16, pre-swizzled source.
__global__ __launch_bounds__(512, 1) void k_gemm8(
    const u16* __restrict__ A1, int lda1, const u16* __restrict__ A2, int lda2, int kstile,
    const u16* __restrict__ Bt, const float* __restrict__ bias1, const float* __restrict__ bias2,
    int Nsplit, float scale1, float scale2, u16* __restrict__ out, int ldc, int K, int gx) {
  __shared__ __align__(16) u16 lds[65536];  // [A|B][buf][half][128*64]
  int tid = threadIdx.x;
  int w = tid >> 6, l = tid & 63;
  int lo = l & 15, hi = l >> 4;
  int wm2 = w >> 2, wn4 = w & 3;
  int nt = K >> 6, niter = nt >> 1;

  // XCD-bijective swizzle (nwg % 8 == 0)
  int nwg = gridDim.x;
  int swz = (blockIdx.x & 7) * (nwg >> 3) + (blockIdx.x >> 3);
  int m0 = (swz / gx) * 256, n0 = (swz % gx) * 256;

  auto ldsA = [&](int buf, int h) -> u16* { return lds + ((buf << 1) + h) * 8192; };
  auto ldsB = [&](int buf, int h) -> u16* { return lds + 32768 + ((buf << 1) + h) * 8192; };

  auto stageA = [&](int tile, int h) {
    int tt = tile < nt ? tile : 0;
    const u16* base; int ldx, kof;
    if (tt < kstile) { base = A1; ldx = lda1; kof = tt * 64; }
    else             { base = A2; ldx = lda2; kof = (tt - kstile) * 64; }
    u16* dst = ldsA(tile & 1, h);
    size_t row0 = (size_t)(m0 + h * 128);
#pragma unroll
    for (int i = 0; i < 2; ++i) {
      int e = i * 4096 + tid * 8;
      int r = e >> 6, s = (e >> 3) & 7;
      gl_lds16(base + (row0 + r) * (size_t)ldx + kof + 8 * (s ^ (r & 7)), dst + e);
    }
  };
  auto stageB = [&](int tile, int h) {
    int tt = tile < nt ? tile : 0;
    u16* dst = ldsB(tile & 1, h);
    size_t row0 = (size_t)(n0 + h * 128);
#pragma unroll
    for (int i = 0; i < 2; ++i) {
      int e = i * 4096 + tid * 8;
      int r = e >> 6, s = (e >> 3) & 7;
      gl_lds16(Bt + (row0 + r) * (size_t)K + tt * 64 + 8 * (s ^ (r & 7)), dst + e);
    }
  };
  auto loadA = [&](bf16x8 (&a)[4][2], int buf, int qm) {
    const u16* src = ldsA(buf, qm);
#pragma unroll
    for (int mf = 0; mf < 4; ++mf) {
      int r = wm2 * 64 + mf * 16 + lo;
#pragma unroll
      for (int kk = 0; kk < 2; ++kk)
        a[mf][kk] = *(const bf16x8*)&src[r * 64 + (((kk * 4 + hi) ^ (r & 7)) << 3)];
    }
  };
  auto loadB = [&](bf16x8 (&bq)[2][2], int buf, int qn) {
    const u16* src = ldsB(buf, qn);
#pragma unroll
    for (int nf = 0; nf < 2; ++nf) {
      int r = wn4 * 32 + nf * 16 + lo;
#pragma unroll
      for (int kk = 0; kk < 2; ++kk)
        bq[nf][kk] = *(const bf16x8*)&src[r * 64 + (((kk * 4 + hi) ^ (r & 7)) << 3)];
    }
  };

  f32x4 acc00[4][2] = {}, acc01[4][2] = {}, acc10[4][2] = {}, acc11[4][2] = {};
  bf16x8 a[4][2], b0[2][2], b1[2][2];

  auto mmaQ = [&](f32x4 (&accq)[4][2], bf16x8 (&aa)[4][2], bf16x8 (&bb)[2][2]) {
    __builtin_amdgcn_s_setprio(1);
#pragma unroll
    for (int mf = 0; mf < 4; ++mf)
#pragma unroll
      for (int nf = 0; nf < 2; ++nf)
#pragma unroll
        for (int kk = 0; kk < 2; ++kk)
          accq[mf][nf] = __builtin_amdgcn_mfma_f32_16x16x32_bf16(aa[mf][kk], bb[nf][kk], accq[mf][nf], 0, 0, 0);
    __builtin_amdgcn_s_setprio(0);
  };

  // prologue: tile0 (4 halves, buf0) + tile1 h0 halves (buf1); wait tile0
  stageA(0, 0); stageB(0, 0); stageA(0, 1); stageB(0, 1);
  stageA(1, 0); stageB(1, 0);
  asm volatile("s_waitcnt vmcnt(4)" ::: "memory");
  BAR;

  for (int it = 0; it < niter; ++it) {
    int t0 = 2 * it;
    // PH1: quad(0,0) tile t0 (buf0)
    loadA(a, 0, 0); loadB(b0, 0, 0);
    stageA(t0 + 1, 1);
    FENCE; BAR; WAITL;
    mmaQ(acc00, a, b0);
    FENCE; BAR;
    // PH2: quad(0,1)
    loadB(b1, 0, 1);
    stageB(t0 + 1, 1);
    FENCE; BAR; WAITL;
    mmaQ(acc01, a, b1);
    FENCE; BAR;
    // PH3: quad(1,0)
    loadA(a, 0, 1);
    stageA(t0 + 2, 0);
    FENCE; BAR; WAITL;
    mmaQ(acc10, a, b0);
    FENCE; BAR;
    // PH4: quad(1,1); gate tile t0+1 complete
    stageB(t0 + 2, 0);
    asm volatile("s_waitcnt vmcnt(4)" ::: "memory");
    BAR;
    mmaQ(acc11, a, b1);
    FENCE; BAR;
    // PH5: quad(0,0) tile t0+1 (buf1)
    loadA(a, 1, 0); loadB(b0, 1, 0);
    stageA(t0 + 2, 1);
    FENCE; BAR; WAITL;
    mmaQ(acc00, a, b0);
    FENCE; BAR;
    // PH6: quad(0,1)
    loadB(b1, 1, 1);
    stageB(t0 + 2, 1);
    FENCE; BAR; WAITL;
    mmaQ(acc01, a, b1);
    FENCE; BAR;
    // PH7: quad(1,0)
    loadA(a, 1, 1);
    stageA(t0 + 3, 0);
    FENCE; BAR; WAITL;
    mmaQ(acc10, a, b0);
    FENCE; BAR;
    // PH8: quad(1,1); gate tile t0+2 complete
    stageB(t0 + 3, 0);
    asm volatile("s_waitcnt vmcnt(4)" ::: "memory");
    BAR;
    mmaQ(acc11, a, b1);
    FENCE; BAR;
  }

  auto epi = [&](f32x4 (&accq)[4][2], int qm, int qn) {
#pragma unroll
    for (int mf = 0; mf < 4; ++mf)
#pragma unroll
      for (int nf = 0; nf < 2; ++nf) {
        int col = n0 + qn * 128 + wn4 * 32 + nf * 16 + lo;
        float bb, sc;
        if (col < Nsplit) { bb = bias1[col]; sc = scale1; }
        else              { bb = bias2[col - Nsplit]; sc = scale2; }
        int row = m0 + qm * 128 + wm2 * 64 + mf * 16 + hi * 4;
#pragma unroll
        for (int i = 0; i < 4; ++i)
          out[(size_t)(row + i) * ldc + col] = f2bf((accq[mf][nf][i] + bb) * sc);
      }
  };
  epi(acc00, 0, 0); epi(acc01, 0, 1); epi(acc10, 1, 0); epi(acc11, 1, 1);
}

// ---------------- GEMM (128x128, m97 structure): oproj / FFN2 ----------------
template <bool OUT_BF16>
__global__ __launch_bounds__(256) void k_gemm(
    const u16* __restrict__ A1, int lda1, const u16* __restrict__ A2, int lda2, int Ksplit,
    const u16* __restrict__ Bt,
    const float* __restrict__ bias1, const float* __restrict__ bias2, int Nsplit,
    float scale1, float scale2,
    const float* __restrict__ resid0, const float* __restrict__ resid1, int Msplit,
    void* __restrict__ out, int ldc, int K) {
  __shared__ __align__(16) u16 As[128 * 64];
  __shared__ __align__(16) u16 Bs[128 * 64];
  int tid = threadIdx.x;
  int w = tid >> 6, l = tid & 63;
  int lo = l & 15, hi = l >> 4;
  int m0 = blockIdx.y * 128, n0 = blockIdx.x * 128;
  f32x4 acc[4][4] = {};
  int wm = (w >> 1) * 64, wn = (w & 1) * 64;

  for (int kt = 0; kt < K; kt += 64) {
    const u16* Ab; int lda, kof;
    if (kt < Ksplit) { Ab = A1; lda = lda1; kof = kt; }
    else             { Ab = A2; lda = lda2; kof = kt - Ksplit; }
#pragma unroll
    for (int i = 0; i < 4; ++i) {
      int ebase = (i * 4 + w) * 512;
      int e = ebase + l * 8;
      int r = e >> 6, s = (e >> 3) & 7;
      gl_lds16(Ab + (size_t)(m0 + r) * lda + kof + 8 * (s ^ (r & 7)), &As[ebase]);
    }
#pragma unroll
    for (int i = 0; i < 4; ++i) {
      int ebase = (i * 4 + w) * 512;
      int e = ebase + l * 8;
      int r = e >> 6, s = (e >> 3) & 7;
      gl_lds16(Bt + (size_t)(n0 + r) * K + kt + 8 * (s ^ (r & 7)), &Bs[ebase]);
    }
    __syncthreads();
#pragma unroll
    for (int kk = 0; kk < 2; ++kk) {
      bf16x8 af[4], bfv[4];
#pragma unroll
      for (int m = 0; m < 4; ++m) {
        int r = wm + m * 16 + lo;
        int slot = (kk * 4 + hi) ^ (r & 7);
        af[m] = *(const bf16x8*)&As[r * 64 + slot * 8];
      }
#pragma unroll
      for (int n = 0; n < 4; ++n) {
        int r = wn + n * 16 + lo;
        int slot = (kk * 4 + hi) ^ (r & 7);
        bfv[n] = *(const bf16x8*)&Bs[r * 64 + slot * 8];
      }
#pragma unroll
      for (int m = 0; m < 4; ++m)
#pragma unroll
        for (int n = 0; n < 4; ++n)
          acc[m][n] = __builtin_amdgcn_mfma_f32_16x16x32_bf16(af[m], bfv[n], acc[m][n], 0, 0, 0);
    }
    __syncthreads();
  }

  const float* bias = bias1; float scl = scale1; int coff = 0;
  if (bias2 && n0 >= Nsplit) { bias = bias2; scl = scale2; coff = Nsplit; }
  const float* resid = nullptr; int roff = 0;
  if (resid0) { if (m0 < Msplit) { resid = resid0; roff = 0; } else { resid = resid1; roff = Msplit; } }

#pragma unroll
  for (int m = 0; m < 4; ++m)
#pragma unroll
    for (int n = 0; n < 4; ++n) {
      int Cc_ = n0 + wn + n * 16 + lo;
      float bvv = bias ? bias[Cc_ - coff] : 0.f;
#pragma unroll
      for (int i = 0; i < 4; ++i) {
        int Rr = m0 + wm + m * 16 + hi * 4 + i;
        float v = (acc[m][n][i] + bvv) * scl;
        if (resid) v += resid[(size_t)(Rr - roff) * ldc + Cc_];
        if (OUT_BF16) ((u16*)out)[(size_t)Rr * ldc + Cc_] = f2bf(v);
        else          ((float*)out)[(size_t)Rr * ldc + Cc_] = v;
      }
    }
}

// ---------------- flash attention (swapped-QK^T, in-register softmax) ----------------
// z=0: Q=qk(stream0), K=qk(stream1), V=vt1, Out=m0 ; z=1: swapped.
// qk is pre-scaled by sqrt(log2e/8) on both sides -> softmax in exp2 domain.
__global__ __launch_bounds__(256) void k_attn(const u16* __restrict__ qkv,
                                              const u16* __restrict__ vt01,
                                              u16* __restrict__ m01) {
  __shared__ __align__(16) u16 q_lds[64 * 64];
  __shared__ __align__(16) u16 k_lds[2][64 * 64];
  __shared__ __align__(16) u16 v_lds[2][64 * 64];
  __shared__ __align__(16) u16 p_lds[4][16 * 64];
  int z = blockIdx.z;
  const u16* Q  = qkv + (size_t)z * Mc * 2048;
  const u16* Kg = qkv + (size_t)(1 - z) * Mc * 2048;
  const u16* Vt = vt01 + (size_t)(1 - z) * VT_STRIDE;
  u16* Out = m01 + (size_t)z * Mc * Dc;
  int tid = threadIdx.x;
  int w = tid >> 6, l = tid & 63;
  int lo = l & 15, hi = l >> 4;
  int qt = blockIdx.x;
  int bh = blockIdx.y, b = bh >> 4, h = bh & 15;
  size_t rowQ0 = (size_t)b * Nc + qt * 64;

#pragma unroll
  for (int i = 0; i < 2; ++i) {
    int ebase = (i * 4 + w) * 512;
    int e = ebase + l * 8;
    int r = e >> 6, s = (e >> 3) & 7;
    gl_lds16(Q + (rowQ0 + r) * 2048 + h * 64 + 8 * (s ^ (r & 7)), &q_lds[ebase]);
    gl_lds16(Kg + ((size_t)b * Nc + r) * 2048 + h * 64 + 8 * (s ^ (r & 7)), &k_lds[0][ebase]);
    gl_lds16(Vt + ((size_t)bh * 64 + r) * Nc + 8 * (s ^ (r & 7)), &v_lds[0][ebase]);
  }
  __syncthreads();
  bf16x8 qf[2];
#pragma unroll
  for (int c = 0; c < 2; ++c) {
    int r = w * 16 + lo;
    int slot = (c * 4 + hi) ^ (r & 7);
    qf[c] = *(const bf16x8*)&q_lds[r * 64 + slot * 8];
  }

  f32x4 o[4] = {};
  float m_ = -INFINITY, ls = 0.f;
  int cur = 0;

  for (int t = 0; t < Nc / 64; ++t) {
    if (t + 1 < Nc / 64) {
#pragma unroll
      for (int i = 0; i < 2; ++i) {
        int ebase = (i * 4 + w) * 512;
        int e = ebase + l * 8;
        int r = e >> 6, s = (e >> 3) & 7;
        gl_lds16(Kg + ((size_t)b * Nc + (t + 1) * 64 + r) * 2048 + h * 64 + 8 * (s ^ (r & 7)),
                 &k_lds[cur ^ 1][ebase]);
        gl_lds16(Vt + ((size_t)bh * 64 + r) * Nc + (t + 1) * 64 + 8 * (s ^ (r & 7)),
                 &v_lds[cur ^ 1][ebase]);
      }
    }

    f32x4 sf[4] = {};
    __builtin_amdgcn_s_setprio(1);
#pragma unroll
    for (int c = 0; c < 2; ++c)
#pragma unroll
      for (int kt = 0; kt < 4; ++kt) {
        int r = kt * 16 + lo;
        int slot = (c * 4 + hi) ^ (r & 7);
        bf16x8 kb = *(const bf16x8*)&k_lds[cur][r * 64 + slot * 8];
        sf[kt] = __builtin_amdgcn_mfma_f32_16x16x32_bf16(kb, qf[c], sf[kt], 0, 0, 0);
      }
    __builtin_amdgcn_s_setprio(0);

    float tm = sf[0][0];
#pragma unroll
    for (int kt = 0; kt < 4; ++kt)
#pragma unroll
      for (int i = 0; i < 4; ++i) tm = fmaxf(tm, sf[kt][i]);
    tm = fmaxf(tm, __shfl_xor(tm, 16));
    tm = fmaxf(tm, __shfl_xor(tm, 32));

    bool defer = __all(tm <= m_ + 8.0f);
    float mn = defer ? m_ : fmaxf(m_, tm);

    float ps = 0.f;
#pragma unroll
    for (int kt = 0; kt < 4; ++kt)
#pragma unroll
      for (int i = 0; i < 4; ++i) {
        float pp = exp2f(sf[kt][i] - mn);
        sf[kt][i] = pp;
        ps += pp;
      }
    ps += __shfl_xor(ps, 16);
    ps += __shfl_xor(ps, 32);

    if (defer) {
      ls += ps;
    } else {
      float alpha = exp2f(m_ - mn);
      ls = ls * alpha + ps;
      m_ = mn;
      float a0 = __shfl(alpha, hi * 4 + 0);
      float a1 = __shfl(alpha, hi * 4 + 1);
      float a2 = __shfl(alpha, hi * 4 + 2);
      float a3 = __shfl(alpha, hi * 4 + 3);
#pragma unroll
      for (int dt = 0; dt < 4; ++dt) {
        o[dt][0] *= a0; o[dt][1] *= a1; o[dt][2] *= a2; o[dt][3] *= a3;
      }
    }

#pragma unroll
    for (int kt = 0; kt < 4; ++kt)
#pragma unroll
      for (int i2 = 0; i2 < 4; i2 += 2) {
        u32 pk;
        asm("v_cvt_pk_bf16_f32 %0, %1, %2" : "=v"(pk) : "v"(sf[kt][i2]), "v"(sf[kt][i2 + 1]));
        int k = kt * 16 + hi * 4 + i2;
        int byte = ((((k >> 3) ^ (lo & 7)) << 4) | ((hi & 1) << 3) | (i2 << 1));
        *(u32*)((char*)&p_lds[w][0] + lo * 128 + byte) = pk;
      }

    __builtin_amdgcn_s_setprio(1);
#pragma unroll
    for (int ks = 0; ks < 2; ++ks) {
      int slotp = (ks * 4 + hi) ^ (lo & 7);
      bf16x8 pa = *(const bf16x8*)&p_lds[w][lo * 64 + slotp * 8];
#pragma unroll
      for (int dt = 0; dt < 4; ++dt) {
        int r = dt * 16 + lo;
        int slot = (ks * 4 + hi) ^ (r & 7);
        bf16x8 vb = *(const bf16x8*)&v_lds[cur][r * 64 + slot * 8];
        o[dt] = __builtin_amdgcn_mfma_f32_16x16x32_bf16(pa, vb, o[dt], 0, 0, 0);
      }
    }
    __builtin_amdgcn_s_setprio(0);

    __syncthreads();
    cur ^= 1;
  }

  float i0 = 1.f / __shfl(ls, hi * 4 + 0);
  float i1 = 1.f / __shfl(ls, hi * 4 + 1);
  float i2 = 1.f / __shfl(ls, hi * 4 + 2);
  float i3 = 1.f / __shfl(ls, hi * 4 + 3);
#pragma unroll
  for (int dt = 0; dt < 4; ++dt) {
    int Rr = qt * 64 + w * 16 + hi * 4;
    Out[((size_t)b * Nc + Rr + 0) * Dc + h * 64 + dt * 16 + lo] = f2bf(o[dt][0] * i0);
    Out[((size_t)b * Nc + Rr + 1) * Dc + h * 64 + dt * 16 + lo] = f2bf(o[dt][1] * i1);
    Out[((size_t)b * Nc + Rr + 2) * Dc + h * 64 + dt * 16 + lo] = f2bf(o[dt][2] * i2);
    Out[((size_t)b * Nc + Rr + 3) * Dc + h * 64 + dt * 16 + lo] = f2bf(o[dt][3] * i3);
  }
}

// ---------------- LayerNorm + exact GeLU, in-place on bf16 [rows][2048] ----------------
__global__ __launch_bounds__(256) void k_ln_gelu(u16* __restrict__ hbuf,
                                                 const float* __restrict__ gamma,
                                                 const float* __restrict__ beta) {
  int row = blockIdx.x;
  u16* hp = hbuf + (size_t)row * D2c;
  int tid = threadIdx.x;
  uint4 raw = *(const uint4*)(hp + tid * 8);
  u16* rs = (u16*)&raw;
  float vals[8];
  float s = 0.f, s2 = 0.f;
#pragma unroll
  for (int j = 0; j < 8; ++j) { float v = bf2f(rs[j]); vals[j] = v; s += v; s2 += v * v; }
#pragma unroll
  for (int off = 1; off < 64; off <<= 1) { s += __shfl_xor(s, off); s2 += __shfl_xor(s2, off); }
  __shared__ float red[2][4];
  int w = tid >> 6, l = tid & 63;
  if (l == 0) { red[0][w] = s; red[1][w] = s2; }
  __syncthreads();
  s = red[0][0] + red[0][1] + red[0][2] + red[0][3];
  s2 = red[1][0] + red[1][1] + red[1][2] + red[1][3];
  float mu = s / D2c;
  float var = s2 / D2c - mu * mu;
  float rstd = rsqrtf(var + 1e-5f);
  union { u16 s[8]; uint4 v; } outp;
#pragma unroll
  for (int j = 0; j < 8; ++j) {
    int c = tid * 8 + j;
    float v = (vals[j] - mu) * rstd * gamma[c] + beta[c];
    float g = 0.5f * v * (1.f + erff(v * 0.70710678118654752f));
    outp.s[j] = f2bf(g);
  }
  *(uint4*)(hp + tid * 8) = outp.v;
}

extern "C" void kernel_launch(void* const* d_in, const int* in_sizes, int n_in,
                              void* d_out, int out_size, void* d_ws, size_t ws_size,
                              hipStream_t stream) {
  const float* x0   = (const float*)d_in[0];
  const float* x1   = (const float*)d_in[1];
  const float* Wqk  = (const float*)d_in[2];
  const float* bqk  = (const float*)d_in[3];
  const float* Wv   = (const float*)d_in[4];
  const float* bv   = (const float*)d_in[5];
  const float* Wo   = (const float*)d_in[6];
  const float* bo   = (const float*)d_in[7];
  const float* Wf1  = (const float*)d_in[8];
  const float* bf1  = (const float*)d_in[9];
  const float* gamma= (const float*)d_in[10];
  const float* beta = (const float*)d_in[11];
  const float* Wf2  = (const float*)d_in[12];
  const float* bf2  = (const float*)d_in[13];
  float* y = (float*)d_out;

  char* p = (char*)d_ws;
  auto take = [&](size_t elems) { u16* r = (u16*)p; p += ((elems * 2 + 255) & ~(size_t)255); return r; };
  u16* Wqkvt = take((size_t)2048 * 1024);   // rows 0..1023 = Wqk^T, 1024..2047 = Wv^T
  u16* Wot   = take((size_t)1024 * 1024);
  u16* Wf1t  = take((size_t)2048 * 2048);
  u16* Wf2t  = take((size_t)2048 * 1024);
  u16* x01b  = take((size_t)8192 * 1024);
  u16* qkv   = take((size_t)8192 * 2048);   // later aliased as h01
  u16* vt01  = take(2 * VT_STRIDE);         // later aliased as o01
  u16* m01   = take((size_t)8192 * 1024);
  u16* h01 = qkv;   // FFN1 output (qkv dead after attention)
  u16* o01 = vt01;  // O-proj output (vt dead after attention)

  dim3 blk(256);
  // sqrt(log2(e)/8): applied to both q and k -> S is scaled by log2(e)/8 (exp2-domain softmax)
  const float sq = 0.4246608984f;

  // weight transposes + input converts
  k_transpose_f32_bf16<<<dim3(16, 16), blk, 0, stream>>>(Wqk, Wqkvt, 1024, 1024);
  k_transpose_f32_bf16<<<dim3(16, 16), blk, 0, stream>>>(Wv, Wqkvt + (size_t)1024 * 1024, 1024, 1024);
  k_transpose_f32_bf16<<<dim3(16, 16), blk, 0, stream>>>(Wo, Wot, 1024, 1024);
  k_transpose_f32_bf16<<<dim3(32, 32), blk, 0, stream>>>(Wf1, Wf1t, 2048, 2048);
  k_transpose_f32_bf16<<<dim3(16, 32), blk, 0, stream>>>(Wf2, Wf2t, 2048, 1024);
  k_f32_to_bf16<<<dim3(2048), blk, 0, stream>>>(x0, x01b, 4096 * 1024);
  k_f32_to_bf16<<<dim3(2048), blk, 0, stream>>>(x1, x01b + (size_t)4096 * 1024, 4096 * 1024);

  // fused qk+v projection (8-phase 256^2): [8192,1024] x [1024,2048] -> qkv
  k_gemm8<<<dim3(256), dim3(512), 0, stream>>>(
      x01b, 1024, x01b, 1024, 16, Wqkvt,
      bqk, bv, 1024, sq, 1.f, qkv, 2048, 1024, 8);

  // per-head V transpose (both streams)
  k_v_transpose<<<dim3(16, 64, 2), blk, 0, stream>>>(qkv, vt01);

  // cross attention (both directions in one dispatch)
  k_attn<<<dim3(16, 64, 2), blk, 0, stream>>>(qkv, vt01, m01);

  // output projection: [8192,1024] x [1024,1024] -> o01
  k_gemm<true><<<dim3(8, 64), blk, 0, stream>>>(
      m01, 1024, m01, 1024, 1024, Wot,
      bo, nullptr, 1024, 1.f, 1.f, nullptr, nullptr, 0, o01, 1024, 1024);

  // FFN1 on concat([x, o]) (8-phase 256^2): [8192,2048] x [2048,2048] -> h01
  k_gemm8<<<dim3(256), dim3(512), 0, stream>>>(
      x01b, 1024, o01, 1024, 16, Wf1t,
      bf1, nullptr, 2048, 1.f, 1.f, h01, 2048, 2048, 8);

  // LayerNorm + GeLU in place
  k_ln_gelu<<<dim3(8192), blk, 0, stream>>>(h01, gamma, beta);

  // FFN2 + residual -> fp32 outputs (y0 rows 0..4095, y1 rows 4096..8191)
  k_gemm<false><<<dim3(8, 64), blk, 0, stream>>>(
      h01, 2048, h01, 2048, 2048, Wf2t,
      bf2, nullptr, 1024, 1.f, 1.f, x0, x1, 4096, y, 1024, 2048);
}

// Round 5
// 361.994 us; speedup vs baseline: 1.6840x; 1.0526x over previous
//
#include <hip/hip_runtime.h>
#include <hip/hip_bf16.h>

typedef unsigned short u16;
typedef unsigned int u32;
typedef __attribute__((ext_vector_type(8))) short bf16x8;
typedef __attribute__((ext_vector_type(4))) float f32x4;
typedef __attribute__((ext_vector_type(16))) float f32x16;

#define DEV __device__ __forceinline__
#define FENCE asm volatile("" ::: "memory")
#define WAITL asm volatile("s_waitcnt lgkmcnt(0)" ::: "memory")
#define BAR __builtin_amdgcn_s_barrier()

static constexpr int Bc = 4, Nc = 1024, Dc = 1024, Hc = 16, Mc = 4096, D2c = 2048;
static constexpr size_t VT_STRIDE = (size_t)4 * 16 * 64 * 1024;  // per-stream vt elems

DEV u16 f2bf(float f) {
  u32 u = __builtin_bit_cast(u32, f);
  u = (u + 0x7FFFu + ((u >> 16) & 1u)) >> 16;
  return (u16)u;
}
DEV float bf2f(u16 h) { u32 u = ((u32)h) << 16; return __builtin_bit_cast(float, u); }
DEV void gl_lds16(const void* g, void* l) {
  __builtin_amdgcn_global_load_lds((const __attribute__((address_space(1))) u32*)g,
                                   (__attribute__((address_space(3))) u32*)l, 16, 0, 0);
}

// ---------------- fp32 -> bf16 convert (vectorized) ----------------
__global__ __launch_bounds__(256) void k_f32_to_bf16(const float* __restrict__ in,
                                                     u16* __restrict__ out, int n) {
  int i = (blockIdx.x * 256 + threadIdx.x) * 8;
  if (i >= n) return;
  float4 a = *(const float4*)(in + i);
  float4 b = *(const float4*)(in + i + 4);
  union { u16 s[8]; uint4 v; } r;
  r.s[0] = f2bf(a.x); r.s[1] = f2bf(a.y); r.s[2] = f2bf(a.z); r.s[3] = f2bf(a.w);
  r.s[4] = f2bf(b.x); r.s[5] = f2bf(b.y); r.s[6] = f2bf(b.z); r.s[7] = f2bf(b.w);
  *(uint4*)(out + i) = r.v;
}

// ---------------- fp32 [R][C] -> bf16 [C][R] transpose-convert ----------------
__global__ __launch_bounds__(256) void k_transpose_f32_bf16(const float* __restrict__ in,
                                                            u16* __restrict__ out, int R, int C) {
  __shared__ float t[64][65];
  int c0 = blockIdx.x * 64, r0 = blockIdx.y * 64;
  int tid = threadIdx.x;
  int rr = tid >> 4, cc4 = (tid & 15) * 4;
  for (int k = 0; k < 4; ++k) {
    int r = rr + k * 16;
    float4 v = *(const float4*)(in + (size_t)(r0 + r) * C + c0 + cc4);
    t[r][cc4 + 0] = v.x; t[r][cc4 + 1] = v.y; t[r][cc4 + 2] = v.z; t[r][cc4 + 3] = v.w;
  }
  __syncthreads();
  int cw = tid >> 4, rr4 = (tid & 15) * 4;
  for (int k = 0; k < 4; ++k) {
    int c = cw + k * 16;
    union { u16 s[4]; uint2 v; } p;
    for (int j = 0; j < 4; ++j) p.s[j] = f2bf(t[rr4 + j][c]);
    *(uint2*)(out + (size_t)(c0 + c) * R + r0 + rr4) = p.v;
  }
}

// ---------------- v (cols 1024.. of qkv, stride 2048) -> vt [z][B*H*64, N] ----------------
__global__ __launch_bounds__(256) void k_v_transpose(const u16* __restrict__ qkv,
                                                     u16* __restrict__ vt01) {
  __shared__ __align__(16) u16 t[64][80];
  int z = blockIdx.z;
  const u16* v = qkv + (size_t)z * Mc * 2048 + 1024;
  u16* vt = vt01 + (size_t)z * VT_STRIDE;
  int nt = blockIdx.x;
  int bh = blockIdx.y, b = bh >> 4, h = bh & 15;
  int tid = threadIdx.x;
  for (int it = 0; it < 2; ++it) {
    int u = it * 256 + tid; int r = u >> 3, ch = u & 7;
    uint4 raw = *(const uint4*)(v + ((size_t)b * Nc + nt * 64 + r) * 2048 + h * 64 + ch * 8);
    *(uint4*)&t[r][ch * 8] = raw;
  }
  __syncthreads();
  for (int it = 0; it < 2; ++it) {
    int u = it * 256 + tid; int d = u >> 3, nch = u & 7;
    union { u16 s[8]; uint4 v4; } p;
    for (int j = 0; j < 8; ++j) p.s[j] = t[nch * 8 + j][d];
    *(uint4*)(vt + ((size_t)bh * 64 + d) * Nc + nt * 64 + nch * 8) = p.v4;
  }
}

// ---------------- 256x256x64 8-phase GEMM (T2+T3+T4+T5), bf16 out ----------------
__global__ __launch_bounds__(512, 1) void k_gemm8(
    const u16* __restrict__ A1, int lda1, const u16* __restrict__ A2, int lda2, int kstile,
    const u16* __restrict__ Bt, const float* __restrict__ bias1, const float* __restrict__ bias2,
    int Nsplit, float scale1, float scale2, u16* __restrict__ out, int ldc, int K, int gx) {
  __shared__ __align__(16) u16 lds[65536];  // [A|B][buf][half][128*64]
  int tid = threadIdx.x;
  int w = tid >> 6, l = tid & 63;
  int lo = l & 15, hi = l >> 4;
  int wm2 = w >> 2, wn4 = w & 3;
  int nt = K >> 6, niter = nt >> 1;

  int nwg = gridDim.x;
  int swz = (blockIdx.x & 7) * (nwg >> 3) + (blockIdx.x >> 3);
  int m0 = (swz / gx) * 256, n0 = (swz % gx) * 256;

  auto ldsA = [&](int buf, int h) -> u16* { return lds + ((buf << 1) + h) * 8192; };
  auto ldsB = [&](int buf, int h) -> u16* { return lds + 32768 + ((buf << 1) + h) * 8192; };

  auto stageA = [&](int tile, int h) {
    int tt = tile < nt ? tile : 0;
    const u16* base; int ldx, kof;
    if (tt < kstile) { base = A1; ldx = lda1; kof = tt * 64; }
    else             { base = A2; ldx = lda2; kof = (tt - kstile) * 64; }
    u16* dst = ldsA(tile & 1, h);
    size_t row0 = (size_t)(m0 + h * 128);
#pragma unroll
    for (int i = 0; i < 2; ++i) {
      int e = i * 4096 + tid * 8;
      int r = e >> 6, s = (e >> 3) & 7;
      gl_lds16(base + (row0 + r) * (size_t)ldx + kof + 8 * (s ^ (r & 7)), dst + e);
    }
  };
  auto stageB = [&](int tile, int h) {
    int tt = tile < nt ? tile : 0;
    u16* dst = ldsB(tile & 1, h);
    size_t row0 = (size_t)(n0 + h * 128);
#pragma unroll
    for (int i = 0; i < 2; ++i) {
      int e = i * 4096 + tid * 8;
      int r = e >> 6, s = (e >> 3) & 7;
      gl_lds16(Bt + (row0 + r) * (size_t)K + tt * 64 + 8 * (s ^ (r & 7)), dst + e);
    }
  };
  auto loadA = [&](bf16x8 (&a)[4][2], int buf, int qm) {
    const u16* src = ldsA(buf, qm);
#pragma unroll
    for (int mf = 0; mf < 4; ++mf) {
      int r = wm2 * 64 + mf * 16 + lo;
#pragma unroll
      for (int kk = 0; kk < 2; ++kk)
        a[mf][kk] = *(const bf16x8*)&src[r * 64 + (((kk * 4 + hi) ^ (r & 7)) << 3)];
    }
  };
  auto loadB = [&](bf16x8 (&bq)[2][2], int buf, int qn) {
    const u16* src = ldsB(buf, qn);
#pragma unroll
    for (int nf = 0; nf < 2; ++nf) {
      int r = wn4 * 32 + nf * 16 + lo;
#pragma unroll
      for (int kk = 0; kk < 2; ++kk)
        bq[nf][kk] = *(const bf16x8*)&src[r * 64 + (((kk * 4 + hi) ^ (r & 7)) << 3)];
    }
  };

  f32x4 acc00[4][2] = {}, acc01[4][2] = {}, acc10[4][2] = {}, acc11[4][2] = {};
  bf16x8 a[4][2], b0[2][2], b1[2][2];

  auto mmaQ = [&](f32x4 (&accq)[4][2], bf16x8 (&aa)[4][2], bf16x8 (&bb)[2][2]) {
    __builtin_amdgcn_s_setprio(1);
#pragma unroll
    for (int mf = 0; mf < 4; ++mf)
#pragma unroll
      for (int nf = 0; nf < 2; ++nf)
#pragma unroll
        for (int kk = 0; kk < 2; ++kk)
          accq[mf][nf] = __builtin_amdgcn_mfma_f32_16x16x32_bf16(aa[mf][kk], bb[nf][kk], accq[mf][nf], 0, 0, 0);
    __builtin_amdgcn_s_setprio(0);
  };

  stageA(0, 0); stageB(0, 0); stageA(0, 1); stageB(0, 1);
  stageA(1, 0); stageB(1, 0);
  asm volatile("s_waitcnt vmcnt(4)" ::: "memory");
  BAR;

  for (int it = 0; it < niter; ++it) {
    int t0 = 2 * it;
    loadA(a, 0, 0); loadB(b0, 0, 0);
    stageA(t0 + 1, 1);
    FENCE; BAR; WAITL;
    mmaQ(acc00, a, b0);
    FENCE; BAR;
    loadB(b1, 0, 1);
    stageB(t0 + 1, 1);
    FENCE; BAR; WAITL;
    mmaQ(acc01, a, b1);
    FENCE; BAR;
    loadA(a, 0, 1);
    stageA(t0 + 2, 0);
    FENCE; BAR; WAITL;
    mmaQ(acc10, a, b0);
    FENCE; BAR;
    stageB(t0 + 2, 0);
    asm volatile("s_waitcnt vmcnt(4)" ::: "memory");
    BAR;
    mmaQ(acc11, a, b1);
    FENCE; BAR;
    loadA(a, 1, 0); loadB(b0, 1, 0);
    stageA(t0 + 2, 1);
    FENCE; BAR; WAITL;
    mmaQ(acc00, a, b0);
    FENCE; BAR;
    loadB(b1, 1, 1);
    stageB(t0 + 2, 1);
    FENCE; BAR; WAITL;
    mmaQ(acc01, a, b1);
    FENCE; BAR;
    loadA(a, 1, 1);
    stageA(t0 + 3, 0);
    FENCE; BAR; WAITL;
    mmaQ(acc10, a, b0);
    FENCE; BAR;
    stageB(t0 + 3, 0);
    asm volatile("s_waitcnt vmcnt(4)" ::: "memory");
    BAR;
    mmaQ(acc11, a, b1);
    FENCE; BAR;
  }

  auto epi = [&](f32x4 (&accq)[4][2], int qm, int qn) {
#pragma unroll
    for (int mf = 0; mf < 4; ++mf)
#pragma unroll
      for (int nf = 0; nf < 2; ++nf) {
        int col = n0 + qn * 128 + wn4 * 32 + nf * 16 + lo;
        float bb, sc;
        if (col < Nsplit) { bb = bias1[col]; sc = scale1; }
        else              { bb = bias2[col - Nsplit]; sc = scale2; }
        int row = m0 + qm * 128 + wm2 * 64 + mf * 16 + hi * 4;
#pragma unroll
        for (int i = 0; i < 4; ++i)
          out[(size_t)(row + i) * ldc + col] = f2bf((accq[mf][nf][i] + bb) * sc);
      }
  };
  epi(acc00, 0, 0); epi(acc01, 0, 1); epi(acc10, 1, 0); epi(acc11, 1, 1);
}

// ---------------- GEMM (128x128, m97 structure): oproj / FFN2 ----------------
template <bool OUT_BF16>
__global__ __launch_bounds__(256) void k_gemm(
    const u16* __restrict__ A1, int lda1, const u16* __restrict__ A2, int lda2, int Ksplit,
    const u16* __restrict__ Bt,
    const float* __restrict__ bias1, const float* __restrict__ bias2, int Nsplit,
    float scale1, float scale2,
    const float* __restrict__ resid0, const float* __restrict__ resid1, int Msplit,
    void* __restrict__ out, int ldc, int K) {
  __shared__ __align__(16) u16 As[128 * 64];
  __shared__ __align__(16) u16 Bs[128 * 64];
  int tid = threadIdx.x;
  int w = tid >> 6, l = tid & 63;
  int lo = l & 15, hi = l >> 4;
  int m0 = blockIdx.y * 128, n0 = blockIdx.x * 128;
  f32x4 acc[4][4] = {};
  int wm = (w >> 1) * 64, wn = (w & 1) * 64;

  for (int kt = 0; kt < K; kt += 64) {
    const u16* Ab; int lda, kof;
    if (kt < Ksplit) { Ab = A1; lda = lda1; kof = kt; }
    else             { Ab = A2; lda = lda2; kof = kt - Ksplit; }
#pragma unroll
    for (int i = 0; i < 4; ++i) {
      int ebase = (i * 4 + w) * 512;
      int e = ebase + l * 8;
      int r = e >> 6, s = (e >> 3) & 7;
      gl_lds16(Ab + (size_t)(m0 + r) * lda + kof + 8 * (s ^ (r & 7)), &As[ebase]);
    }
#pragma unroll
    for (int i = 0; i < 4; ++i) {
      int ebase = (i * 4 + w) * 512;
      int e = ebase + l * 8;
      int r = e >> 6, s = (e >> 3) & 7;
      gl_lds16(Bt + (size_t)(n0 + r) * K + kt + 8 * (s ^ (r & 7)), &Bs[ebase]);
    }
    __syncthreads();
#pragma unroll
    for (int kk = 0; kk < 2; ++kk) {
      bf16x8 af[4], bfv[4];
#pragma unroll
      for (int m = 0; m < 4; ++m) {
        int r = wm + m * 16 + lo;
        int slot = (kk * 4 + hi) ^ (r & 7);
        af[m] = *(const bf16x8*)&As[r * 64 + slot * 8];
      }
#pragma unroll
      for (int n = 0; n < 4; ++n) {
        int r = wn + n * 16 + lo;
        int slot = (kk * 4 + hi) ^ (r & 7);
        bfv[n] = *(const bf16x8*)&Bs[r * 64 + slot * 8];
      }
#pragma unroll
      for (int m = 0; m < 4; ++m)
#pragma unroll
        for (int n = 0; n < 4; ++n)
          acc[m][n] = __builtin_amdgcn_mfma_f32_16x16x32_bf16(af[m], bfv[n], acc[m][n], 0, 0, 0);
    }
    __syncthreads();
  }

  const float* bias = bias1; float scl = scale1; int coff = 0;
  if (bias2 && n0 >= Nsplit) { bias = bias2; scl = scale2; coff = Nsplit; }
  const float* resid = nullptr; int roff = 0;
  if (resid0) { if (m0 < Msplit) { resid = resid0; roff = 0; } else { resid = resid1; roff = Msplit; } }

#pragma unroll
  for (int m = 0; m < 4; ++m)
#pragma unroll
    for (int n = 0; n < 4; ++n) {
      int Cc_ = n0 + wn + n * 16 + lo;
      float bvv = bias ? bias[Cc_ - coff] : 0.f;
#pragma unroll
      for (int i = 0; i < 4; ++i) {
        int Rr = m0 + wm + m * 16 + hi * 4 + i;
        float v = (acc[m][n][i] + bvv) * scl;
        if (resid) v += resid[(size_t)(Rr - roff) * ldc + Cc_];
        if (OUT_BF16) ((u16*)out)[(size_t)Rr * ldc + Cc_] = f2bf(v);
        else          ((float*)out)[(size_t)Rr * ldc + Cc_] = v;
      }
    }
}

// ---------------- flash attention: 8 waves x 32q, 32x32x16 MFMA, P in-register ----------------
// S = mfma(K, Q) -> S[k][q], q = lane&31.  O^T = mfma(V^T, P) -> O^T[d][q], q = lane&31.
// P fragments built via v_cvt_pk_bf16_f32 + v_permlane32_swap_b32 (no LDS round-trip).
// qk pre-scaled by sqrt(log2e/8) on both sides -> softmax in exp2 domain.
__global__ __launch_bounds__(512, 2) void k_attn(const u16* __restrict__ qkv,
                                                 const u16* __restrict__ vt01,
                                                 u16* __restrict__ m01) {
  __shared__ __align__(16) u16 q_lds[256 * 64];
  __shared__ __align__(16) u16 k_lds[2][64 * 64];
  __shared__ __align__(16) u16 v_lds[2][64 * 64];
  int z = blockIdx.z;
  const u16* Q  = qkv + (size_t)z * Mc * 2048;
  const u16* Kg = qkv + (size_t)(1 - z) * Mc * 2048;
  const u16* Vt = vt01 + (size_t)(1 - z) * VT_STRIDE;
  u16* Out = m01 + (size_t)z * Mc * Dc;
  int tid = threadIdx.x;
  int w = tid >> 6, l = tid & 63;
  int q31 = l & 31, h = l >> 5;
  int qt = blockIdx.x;
  int bh = blockIdx.y, b = bh >> 4, hd = bh & 15;
  size_t rowQ0 = (size_t)b * Nc + qt * 256;

  // prologue: stage Q (256x64) + K/V tile 0
  {
    int r = tid >> 3, s = tid & 7;
#pragma unroll
    for (int c = 0; c < 4; ++c)
      gl_lds16(Q + (rowQ0 + c * 64 + r) * 2048 + hd * 64 + 8 * (s ^ (r & 7)),
               &q_lds[(size_t)(c * 512 + tid) * 8]);
    gl_lds16(Kg + ((size_t)b * Nc + r) * 2048 + hd * 64 + 8 * (s ^ (r & 7)), &k_lds[0][(size_t)tid * 8]);
    gl_lds16(Vt + ((size_t)bh * 64 + r) * Nc + 8 * (s ^ (r & 7)), &v_lds[0][(size_t)tid * 8]);
  }
  __syncthreads();

  // Q B-frags (hoisted): B[d][q], q=lane&31, d = dk*16 + h*8 + j
  bf16x8 qf[4];
  {
    int row = w * 32 + q31;
#pragma unroll
    for (int dk = 0; dk < 4; ++dk)
      qf[dk] = *(const bf16x8*)&q_lds[row * 64 + (((dk * 2 + h) ^ (row & 7)) << 3)];
  }

  f32x16 o0 = {}, o1 = {};
  float m_ = -INFINITY, ls = 0.f;
  int cur = 0;

  for (int t = 0; t < Nc / 64; ++t) {
    // async-stage next K/V tile
    if (t + 1 < Nc / 64) {
      int r = tid >> 3, s = tid & 7;
      gl_lds16(Kg + ((size_t)b * Nc + (t + 1) * 64 + r) * 2048 + hd * 64 + 8 * (s ^ (r & 7)),
               &k_lds[cur ^ 1][(size_t)tid * 8]);
      gl_lds16(Vt + ((size_t)bh * 64 + r) * Nc + (t + 1) * 64 + 8 * (s ^ (r & 7)),
               &v_lds[cur ^ 1][(size_t)tid * 8]);
    }

    // QK^T swapped: s_acc[kt] = S[k = t*64 + kt*32 + crow(reg,h)][q = q31]
    f32x16 s0 = {}, s1 = {};
    __builtin_amdgcn_s_setprio(1);
#pragma unroll
    for (int dk = 0; dk < 4; ++dk) {
      int r0 = q31, r1 = 32 + q31;
      bf16x8 k0 = *(const bf16x8*)&k_lds[cur][r0 * 64 + (((dk * 2 + h) ^ (r0 & 7)) << 3)];
      bf16x8 k1 = *(const bf16x8*)&k_lds[cur][r1 * 64 + (((dk * 2 + h) ^ (r1 & 7)) << 3)];
      s0 = __builtin_amdgcn_mfma_f32_32x32x16_bf16(k0, qf[dk], s0, 0, 0, 0);
      s1 = __builtin_amdgcn_mfma_f32_32x32x16_bf16(k1, qf[dk], s1, 0, 0, 0);
    }
    __builtin_amdgcn_s_setprio(0);

    // row max: 32 in-register + 1 cross-half hop
    float tm = s0[0];
#pragma unroll
    for (int i = 1; i < 16; ++i) tm = fmaxf(tm, s0[i]);
#pragma unroll
    for (int i = 0; i < 16; ++i) tm = fmaxf(tm, s1[i]);
    tm = fmaxf(tm, __shfl_xor(tm, 32));

    bool defer = __all(tm <= m_ + 8.0f);
    float mn = defer ? m_ : fmaxf(m_, tm);

    float ps = 0.f;
#pragma unroll
    for (int i = 0; i < 16; ++i) { float p = exp2f(s0[i] - mn); s0[i] = p; ps += p; }
#pragma unroll
    for (int i = 0; i < 16; ++i) { float p = exp2f(s1[i] - mn); s1[i] = p; ps += p; }
    ps += __shfl_xor(ps, 32);

    if (defer) {
      ls += ps;
    } else {
      float alpha = exp2f(m_ - mn);
      ls = ls * alpha + ps;
      m_ = mn;
      o0 *= alpha; o1 *= alpha;   // O^T cols = own q -> no cross-lane
    }

    // pack P: pk[kt][a][c2] = bf16 pair at k = kt*32 + 8a + 4h + 2c2
    u32 pk0[4][2], pk1[4][2];
#pragma unroll
    for (int a2 = 0; a2 < 4; ++a2)
#pragma unroll
      for (int c2 = 0; c2 < 2; ++c2) {
        asm("v_cvt_pk_bf16_f32 %0, %1, %2" : "=v"(pk0[a2][c2]) : "v"(s0[4 * a2 + 2 * c2]), "v"(s0[4 * a2 + 2 * c2 + 1]));
        asm("v_cvt_pk_bf16_f32 %0, %1, %2" : "=v"(pk1[a2][c2]) : "v"(s1[4 * a2 + 2 * c2]), "v"(s1[4 * a2 + 2 * c2 + 1]));
      }
    // P B-frags: frag[ks] needs k = ks*16 + h*8 + 0..7; one permlane pair per (ks,c2)
    bf16x8 pf[4];
#pragma unroll
    for (int ks = 0; ks < 4; ++ks) {
      const int aE = (2 * ks) & 3, aO = (2 * ks + 1) & 3;
      u32 x0, y0, x1, y1;
      if (ks < 2) { x0 = pk0[aE][0]; y0 = pk0[aO][0]; x1 = pk0[aE][1]; y1 = pk0[aO][1]; }
      else        { x0 = pk1[aE][0]; y0 = pk1[aO][0]; x1 = pk1[aE][1]; y1 = pk1[aO][1]; }
      asm("v_permlane32_swap_b32 %0, %1" : "+v"(x0), "+v"(y0));
      asm("v_permlane32_swap_b32 %0, %1" : "+v"(x1), "+v"(y1));
      union { u32 u[4]; bf16x8 v; } fu;
      fu.u[0] = x0; fu.u[1] = x1; fu.u[2] = y0; fu.u[3] = y1;
      pf[ks] = fu.v;
    }

    // PV swapped: O^T[d][q] += V^T-frag x P-frag
    __builtin_amdgcn_s_setprio(1);
#pragma unroll
    for (int ks = 0; ks < 4; ++ks) {
      int r0 = q31, r1 = 32 + q31;
      bf16x8 v0 = *(const bf16x8*)&v_lds[cur][r0 * 64 + (((ks * 2 + h) ^ (r0 & 7)) << 3)];
      bf16x8 v1 = *(const bf16x8*)&v_lds[cur][r1 * 64 + (((ks * 2 + h) ^ (r1 & 7)) << 3)];
      o0 = __builtin_amdgcn_mfma_f32_32x32x16_bf16(v0, pf[ks], o0, 0, 0, 0);
      o1 = __builtin_amdgcn_mfma_f32_32x32x16_bf16(v1, pf[ks], o1, 0, 0, 0);
    }
    __builtin_amdgcn_s_setprio(0);

    __syncthreads();  // drains next-tile stage loads + all waves done with k/v_lds[cur]
    cur ^= 1;
  }

  // epilogue: O^T[d][q=q31] / ls -> Out[q][d]; d = dt*32 + 8*rq + 4h + c
  float inv = 1.f / ls;
  int q_abs = qt * 256 + w * 32 + q31;
  u16* orow = Out + ((size_t)b * Nc + q_abs) * Dc + hd * 64;
#pragma unroll
  for (int rq = 0; rq < 4; ++rq) {
    union { u16 s[4]; uint2 v; } p0, p1;
#pragma unroll
    for (int c = 0; c < 4; ++c) {
      p0.s[c] = f2bf(o0[4 * rq + c] * inv);
      p1.s[c] = f2bf(o1[4 * rq + c] * inv);
    }
    *(uint2*)(orow + 8 * rq + 4 * h) = p0.v;
    *(uint2*)(orow + 32 + 8 * rq + 4 * h) = p1.v;
  }
}

// ---------------- LayerNorm + exact GeLU, in-place on bf16 [rows][2048] ----------------
__global__ __launch_bounds__(256) void k_ln_gelu(u16* __restrict__ hbuf,
                                                 const float* __restrict__ gamma,
                                                 const float* __restrict__ beta) {
  int row = blockIdx.x;
  u16* hp = hbuf + (size_t)row * D2c;
  int tid = threadIdx.x;
  uint4 raw = *(const uint4*)(hp + tid * 8);
  u16* rs = (u16*)&raw;
  float vals[8];
  float s = 0.f, s2 = 0.f;
#pragma unroll
  for (int j = 0; j < 8; ++j) { float v = bf2f(rs[j]); vals[j] = v; s += v; s2 += v * v; }
#pragma unroll
  for (int off = 1; off < 64; off <<= 1) { s += __shfl_xor(s, off); s2 += __shfl_xor(s2, off); }
  __shared__ float red[2][4];
  int w = tid >> 6, l = tid & 63;
  if (l == 0) { red[0][w] = s; red[1][w] = s2; }
  __syncthreads();
  s = red[0][0] + red[0][1] + red[0][2] + red[0][3];
  s2 = red[1][0] + red[1][1] + red[1][2] + red[1][3];
  float mu = s / D2c;
  float var = s2 / D2c - mu * mu;
  float rstd = rsqrtf(var + 1e-5f);
  union { u16 s[8]; uint4 v; } outp;
#pragma unroll
  for (int j = 0; j < 8; ++j) {
    int c = tid * 8 + j;
    float v = (vals[j] - mu) * rstd * gamma[c] + beta[c];
    float g = 0.5f * v * (1.f + erff(v * 0.70710678118654752f));
    outp.s[j] = f2bf(g);
  }
  *(uint4*)(hp + tid * 8) = outp.v;
}

extern "C" void kernel_launch(void* const* d_in, const int* in_sizes, int n_in,
                              void* d_out, int out_size, void* d_ws, size_t ws_size,
                              hipStream_t stream) {
  const float* x0   = (const float*)d_in[0];
  const float* x1   = (const float*)d_in[1];
  const float* Wqk  = (const float*)d_in[2];
  const float* bqk  = (const float*)d_in[3];
  const float* Wv   = (const float*)d_in[4];
  const float* bv   = (const float*)d_in[5];
  const float* Wo   = (const float*)d_in[6];
  const float* bo   = (const float*)d_in[7];
  const float* Wf1  = (const float*)d_in[8];
  const float* bf1  = (const float*)d_in[9];
  const float* gamma= (const float*)d_in[10];
  const float* beta = (const float*)d_in[11];
  const float* Wf2  = (const float*)d_in[12];
  const float* bf2  = (const float*)d_in[13];
  float* y = (float*)d_out;

  char* p = (char*)d_ws;
  auto take = [&](size_t elems) { u16* r = (u16*)p; p += ((elems * 2 + 255) & ~(size_t)255); return r; };
  u16* Wqkvt = take((size_t)2048 * 1024);   // rows 0..1023 = Wqk^T, 1024..2047 = Wv^T
  u16* Wot   = take((size_t)1024 * 1024);
  u16* Wf1t  = take((size_t)2048 * 2048);
  u16* Wf2t  = take((size_t)2048 * 1024);
  u16* x01b  = take((size_t)8192 * 1024);
  u16* qkv   = take((size_t)8192 * 2048);   // later aliased as h01
  u16* vt01  = take(2 * VT_STRIDE);         // later aliased as o01
  u16* m01   = take((size_t)8192 * 1024);
  u16* h01 = qkv;   // FFN1 output (qkv dead after attention)
  u16* o01 = vt01;  // O-proj output (vt dead after attention)

  dim3 blk(256);
  // sqrt(log2(e)/8): applied to both q and k -> S is scaled by log2(e)/8 (exp2-domain softmax)
  const float sq = 0.4246608984f;

  // weight transposes + input converts
  k_transpose_f32_bf16<<<dim3(16, 16), blk, 0, stream>>>(Wqk, Wqkvt, 1024, 1024);
  k_transpose_f32_bf16<<<dim3(16, 16), blk, 0, stream>>>(Wv, Wqkvt + (size_t)1024 * 1024, 1024, 1024);
  k_transpose_f32_bf16<<<dim3(16, 16), blk, 0, stream>>>(Wo, Wot, 1024, 1024);
  k_transpose_f32_bf16<<<dim3(32, 32), blk, 0, stream>>>(Wf1, Wf1t, 2048, 2048);
  k_transpose_f32_bf16<<<dim3(16, 32), blk, 0, stream>>>(Wf2, Wf2t, 2048, 1024);
  k_f32_to_bf16<<<dim3(2048), blk, 0, stream>>>(x0, x01b, 4096 * 1024);
  k_f32_to_bf16<<<dim3(2048), blk, 0, stream>>>(x1, x01b + (size_t)4096 * 1024, 4096 * 1024);

  // fused qk+v projection (8-phase 256^2): [8192,1024] x [1024,2048] -> qkv
  k_gemm8<<<dim3(256), dim3(512), 0, stream>>>(
      x01b, 1024, x01b, 1024, 16, Wqkvt,
      bqk, bv, 1024, sq, 1.f, qkv, 2048, 1024, 8);

  // per-head V transpose (both streams)
  k_v_transpose<<<dim3(16, 64, 2), blk, 0, stream>>>(qkv, vt01);

  // cross attention (both directions in one dispatch)
  k_attn<<<dim3(4, 64, 2), dim3(512), 0, stream>>>(qkv, vt01, m01);

  // output projection: [8192,1024] x [1024,1024] -> o01
  k_gemm<true><<<dim3(8, 64), blk, 0, stream>>>(
      m01, 1024, m01, 1024, 1024, Wot,
      bo, nullptr, 1024, 1.f, 1.f, nullptr, nullptr, 0, o01, 1024, 1024);

  // FFN1 on concat([x, o]) (8-phase 256^2): [8192,2048] x [2048,2048] -> h01
  k_gemm8<<<dim3(256), dim3(512), 0, stream>>>(
      x01b, 1024, o01, 1024, 16, Wf1t,
      bf1, nullptr, 2048, 1.f, 1.f, h01, 2048, 2048, 8);

  // LayerNorm + GeLU in place
  k_ln_gelu<<<dim3(8192), blk, 0, stream>>>(h01, gamma, beta);

  // FFN2 + residual -> fp32 outputs (y0 rows 0..4095, y1 rows 4096..8191)
  k_gemm<false><<<dim3(8, 64), blk, 0, stream>>>(
      h01, 2048, h01, 2048, 2048, Wf2t,
      bf2, nullptr, 1024, 1.f, 1.f, x0, x1, 4096, y, 1024, 2048);
}

// Round 6
// 338.745 us; speedup vs baseline: 1.7996x; 1.0686x over previous
//
#include <hip/hip_runtime.h>
#include <hip/hip_bf16.h>

typedef unsigned short u16;
typedef unsigned int u32;
typedef __attribute__((ext_vector_type(8))) short bf16x8;
typedef __attribute__((ext_vector_type(4))) float f32x4;
typedef __attribute__((ext_vector_type(16))) float f32x16;

#define DEV __device__ __forceinline__
#define FENCE asm volatile("" ::: "memory")
#define WAITL asm volatile("s_waitcnt lgkmcnt(0)" ::: "memory")
#define BAR __builtin_amdgcn_s_barrier()

static constexpr int Bc = 4, Nc = 1024, Dc = 1024, Hc = 16, Mc = 4096, D2c = 2048;
static constexpr size_t VT_STRIDE = (size_t)4 * 16 * 64 * 1024;  // per-stream vt elems

DEV u16 f2bf(float f) {
  u32 u = __builtin_bit_cast(u32, f);
  u = (u + 0x7FFFu + ((u >> 16) & 1u)) >> 16;
  return (u16)u;
}
DEV float bf2f(u16 h) { u32 u = ((u32)h) << 16; return __builtin_bit_cast(float, u); }
DEV void gl_lds16(const void* g, void* l) {
  __builtin_amdgcn_global_load_lds((const __attribute__((address_space(1))) u32*)g,
                                   (__attribute__((address_space(3))) u32*)l, 16, 0, 0);
}

// ---------------- fp32 -> bf16 convert (vectorized) ----------------
__global__ __launch_bounds__(256) void k_f32_to_bf16(const float* __restrict__ in,
                                                     u16* __restrict__ out, int n) {
  int i = (blockIdx.x * 256 + threadIdx.x) * 8;
  if (i >= n) return;
  float4 a = *(const float4*)(in + i);
  float4 b = *(const float4*)(in + i + 4);
  union { u16 s[8]; uint4 v; } r;
  r.s[0] = f2bf(a.x); r.s[1] = f2bf(a.y); r.s[2] = f2bf(a.z); r.s[3] = f2bf(a.w);
  r.s[4] = f2bf(b.x); r.s[5] = f2bf(b.y); r.s[6] = f2bf(b.z); r.s[7] = f2bf(b.w);
  *(uint4*)(out + i) = r.v;
}

// ---------------- fp32 [R][C] -> bf16 [C][R] transpose-convert ----------------
__global__ __launch_bounds__(256) void k_transpose_f32_bf16(const float* __restrict__ in,
                                                            u16* __restrict__ out, int R, int C) {
  __shared__ float t[64][65];
  int c0 = blockIdx.x * 64, r0 = blockIdx.y * 64;
  int tid = threadIdx.x;
  int rr = tid >> 4, cc4 = (tid & 15) * 4;
  for (int k = 0; k < 4; ++k) {
    int r = rr + k * 16;
    float4 v = *(const float4*)(in + (size_t)(r0 + r) * C + c0 + cc4);
    t[r][cc4 + 0] = v.x; t[r][cc4 + 1] = v.y; t[r][cc4 + 2] = v.z; t[r][cc4 + 3] = v.w;
  }
  __syncthreads();
  int cw = tid >> 4, rr4 = (tid & 15) * 4;
  for (int k = 0; k < 4; ++k) {
    int c = cw + k * 16;
    union { u16 s[4]; uint2 v; } p;
    for (int j = 0; j < 4; ++j) p.s[j] = f2bf(t[rr4 + j][c]);
    *(uint2*)(out + (size_t)(c0 + c) * R + r0 + rr4) = p.v;
  }
}

// ---------------- v (cols 1024.. of qkv, stride 2048) -> vt [z][B*H*64, N] ----------------
__global__ __launch_bounds__(256) void k_v_transpose(const u16* __restrict__ qkv,
                                                     u16* __restrict__ vt01) {
  __shared__ __align__(16) u16 t[64][80];
  int z = blockIdx.z;
  const u16* v = qkv + (size_t)z * Mc * 2048 + 1024;
  u16* vt = vt01 + (size_t)z * VT_STRIDE;
  int nt = blockIdx.x;
  int bh = blockIdx.y, b = bh >> 4, h = bh & 15;
  int tid = threadIdx.x;
  for (int it = 0; it < 2; ++it) {
    int u = it * 256 + tid; int r = u >> 3, ch = u & 7;
    uint4 raw = *(const uint4*)(v + ((size_t)b * Nc + nt * 64 + r) * 2048 + h * 64 + ch * 8);
    *(uint4*)&t[r][ch * 8] = raw;
  }
  __syncthreads();
  for (int it = 0; it < 2; ++it) {
    int u = it * 256 + tid; int d = u >> 3, nch = u & 7;
    union { u16 s[8]; uint4 v4; } p;
    for (int j = 0; j < 8; ++j) p.s[j] = t[nch * 8 + j][d];
    *(uint4*)(vt + ((size_t)bh * 64 + d) * Nc + nt * 64 + nch * 8) = p.v4;
  }
}

// ---------------- 256x256x64 8-phase GEMM (T2+T3+T4+T5), bf16 out ----------------
__global__ __launch_bounds__(512, 1) void k_gemm8(
    const u16* __restrict__ A1, int lda1, const u16* __restrict__ A2, int lda2, int kstile,
    const u16* __restrict__ Bt, const float* __restrict__ bias1, const float* __restrict__ bias2,
    int Nsplit, float scale1, float scale2, u16* __restrict__ out, int ldc, int K, int gx) {
  __shared__ __align__(16) u16 lds[65536];  // [A|B][buf][half][128*64]
  int tid = threadIdx.x;
  int w = tid >> 6, l = tid & 63;
  int lo = l & 15, hi = l >> 4;
  int wm2 = w >> 2, wn4 = w & 3;
  int nt = K >> 6, niter = nt >> 1;

  int nwg = gridDim.x;
  int swz = (blockIdx.x & 7) * (nwg >> 3) + (blockIdx.x >> 3);
  int m0 = (swz / gx) * 256, n0 = (swz % gx) * 256;

  auto ldsA = [&](int buf, int h) -> u16* { return lds + ((buf << 1) + h) * 8192; };
  auto ldsB = [&](int buf, int h) -> u16* { return lds + 32768 + ((buf << 1) + h) * 8192; };

  auto stageA = [&](int tile, int h) {
    int tt = tile < nt ? tile : 0;
    const u16* base; int ldx, kof;
    if (tt < kstile) { base = A1; ldx = lda1; kof = tt * 64; }
    else             { base = A2; ldx = lda2; kof = (tt - kstile) * 64; }
    u16* dst = ldsA(tile & 1, h);
    size_t row0 = (size_t)(m0 + h * 128);
#pragma unroll
    for (int i = 0; i < 2; ++i) {
      int e = i * 4096 + tid * 8;
      int r = e >> 6, s = (e >> 3) & 7;
      gl_lds16(base + (row0 + r) * (size_t)ldx + kof + 8 * (s ^ (r & 7)), dst + e);
    }
  };
  auto stageB = [&](int tile, int h) {
    int tt = tile < nt ? tile : 0;
    u16* dst = ldsB(tile & 1, h);
    size_t row0 = (size_t)(n0 + h * 128);
#pragma unroll
    for (int i = 0; i < 2; ++i) {
      int e = i * 4096 + tid * 8;
      int r = e >> 6, s = (e >> 3) & 7;
      gl_lds16(Bt + (row0 + r) * (size_t)K + tt * 64 + 8 * (s ^ (r & 7)), dst + e);
    }
  };
  auto loadA = [&](bf16x8 (&a)[4][2], int buf, int qm) {
    const u16* src = ldsA(buf, qm);
#pragma unroll
    for (int mf = 0; mf < 4; ++mf) {
      int r = wm2 * 64 + mf * 16 + lo;
#pragma unroll
      for (int kk = 0; kk < 2; ++kk)
        a[mf][kk] = *(const bf16x8*)&src[r * 64 + (((kk * 4 + hi) ^ (r & 7)) << 3)];
    }
  };
  auto loadB = [&](bf16x8 (&bq)[2][2], int buf, int qn) {
    const u16* src = ldsB(buf, qn);
#pragma unroll
    for (int nf = 0; nf < 2; ++nf) {
      int r = wn4 * 32 + nf * 16 + lo;
#pragma unroll
      for (int kk = 0; kk < 2; ++kk)
        bq[nf][kk] = *(const bf16x8*)&src[r * 64 + (((kk * 4 + hi) ^ (r & 7)) << 3)];
    }
  };

  f32x4 acc00[4][2] = {}, acc01[4][2] = {}, acc10[4][2] = {}, acc11[4][2] = {};
  bf16x8 a[4][2], b0[2][2], b1[2][2];

  auto mmaQ = [&](f32x4 (&accq)[4][2], bf16x8 (&aa)[4][2], bf16x8 (&bb)[2][2]) {
    __builtin_amdgcn_s_setprio(1);
#pragma unroll
    for (int mf = 0; mf < 4; ++mf)
#pragma unroll
      for (int nf = 0; nf < 2; ++nf)
#pragma unroll
        for (int kk = 0; kk < 2; ++kk)
          accq[mf][nf] = __builtin_amdgcn_mfma_f32_16x16x32_bf16(aa[mf][kk], bb[nf][kk], accq[mf][nf], 0, 0, 0);
    __builtin_amdgcn_s_setprio(0);
  };

  stageA(0, 0); stageB(0, 0); stageA(0, 1); stageB(0, 1);
  stageA(1, 0); stageB(1, 0);
  asm volatile("s_waitcnt vmcnt(4)" ::: "memory");
  BAR;

  for (int it = 0; it < niter; ++it) {
    int t0 = 2 * it;
    loadA(a, 0, 0); loadB(b0, 0, 0);
    stageA(t0 + 1, 1);
    FENCE; BAR; WAITL;
    mmaQ(acc00, a, b0);
    FENCE; BAR;
    loadB(b1, 0, 1);
    stageB(t0 + 1, 1);
    FENCE; BAR; WAITL;
    mmaQ(acc01, a, b1);
    FENCE; BAR;
    loadA(a, 0, 1);
    stageA(t0 + 2, 0);
    FENCE; BAR; WAITL;
    mmaQ(acc10, a, b0);
    FENCE; BAR;
    stageB(t0 + 2, 0);
    asm volatile("s_waitcnt vmcnt(4)" ::: "memory");
    BAR;
    mmaQ(acc11, a, b1);
    FENCE; BAR;
    loadA(a, 1, 0); loadB(b0, 1, 0);
    stageA(t0 + 2, 1);
    FENCE; BAR; WAITL;
    mmaQ(acc00, a, b0);
    FENCE; BAR;
    loadB(b1, 1, 1);
    stageB(t0 + 2, 1);
    FENCE; BAR; WAITL;
    mmaQ(acc01, a, b1);
    FENCE; BAR;
    loadA(a, 1, 1);
    stageA(t0 + 3, 0);
    FENCE; BAR; WAITL;
    mmaQ(acc10, a, b0);
    FENCE; BAR;
    stageB(t0 + 3, 0);
    asm volatile("s_waitcnt vmcnt(4)" ::: "memory");
    BAR;
    mmaQ(acc11, a, b1);
    FENCE; BAR;
  }

  auto epi = [&](f32x4 (&accq)[4][2], int qm, int qn) {
#pragma unroll
    for (int mf = 0; mf < 4; ++mf)
#pragma unroll
      for (int nf = 0; nf < 2; ++nf) {
        int col = n0 + qn * 128 + wn4 * 32 + nf * 16 + lo;
        float bb, sc;
        if (col < Nsplit) { bb = bias1[col]; sc = scale1; }
        else              { bb = bias2[col - Nsplit]; sc = scale2; }
        int row = m0 + qm * 128 + wm2 * 64 + mf * 16 + hi * 4;
#pragma unroll
        for (int i = 0; i < 4; ++i)
          out[(size_t)(row + i) * ldc + col] = f2bf((accq[mf][nf][i] + bb) * sc);
      }
  };
  epi(acc00, 0, 0); epi(acc01, 0, 1); epi(acc10, 1, 0); epi(acc11, 1, 1);
}

// ---------------- 256x128x64 8-phase GEMM variant (for N=1024 outputs) ----------------
// Same schedule as k_gemm8; B-halves are [64][64] (1 load/thread), A-halves [128][64]
// (2 loads/thread) -> 3 loads outstanding after each gate => vmcnt(3).
// Epilogue: bias (+ optional split residual), bf16 or fp32 out.
template <bool OUT_BF16>
__global__ __launch_bounds__(512, 1) void k_gemm8h(
    const u16* __restrict__ A1, int lda1, const u16* __restrict__ Bt,
    const float* __restrict__ bias,
    const float* __restrict__ resid0, const float* __restrict__ resid1, int Msplit,
    void* __restrict__ out, int ldc, int K, int gx) {
  __shared__ __align__(16) u16 lds[49152];  // A: 2buf*2half*8192, B: 2buf*2half*4096
  int tid = threadIdx.x;
  int w = tid >> 6, l = tid & 63;
  int lo = l & 15, hi = l >> 4;
  int wm2 = w >> 2, wn4 = w & 3;
  int nt = K >> 6, niter = nt >> 1;

  int nwg = gridDim.x;
  int swz = (blockIdx.x & 7) * (nwg >> 3) + (blockIdx.x >> 3);
  int m0 = (swz / gx) * 256, n0 = (swz % gx) * 128;

  auto ldsA = [&](int buf, int h) -> u16* { return lds + ((buf << 1) + h) * 8192; };
  auto ldsB = [&](int buf, int h) -> u16* { return lds + 32768 + ((buf << 1) + h) * 4096; };

  auto stageA = [&](int tile, int h) {
    int tt = tile < nt ? tile : 0;
    u16* dst = ldsA(tile & 1, h);
    size_t row0 = (size_t)(m0 + h * 128);
#pragma unroll
    for (int i = 0; i < 2; ++i) {
      int e = i * 4096 + tid * 8;
      int r = e >> 6, s = (e >> 3) & 7;
      gl_lds16(A1 + (row0 + r) * (size_t)lda1 + tt * 64 + 8 * (s ^ (r & 7)), dst + e);
    }
  };
  auto stageB = [&](int tile, int h) {
    int tt = tile < nt ? tile : 0;
    u16* dst = ldsB(tile & 1, h);
    size_t row0 = (size_t)(n0 + h * 64);
    int e = tid * 8;
    int r = e >> 6, s = (e >> 3) & 7;
    gl_lds16(Bt + (row0 + r) * (size_t)K + tt * 64 + 8 * (s ^ (r & 7)), dst + e);
  };
  auto loadA = [&](bf16x8 (&a)[4][2], int buf, int qm) {
    const u16* src = ldsA(buf, qm);
#pragma unroll
    for (int mf = 0; mf < 4; ++mf) {
      int r = wm2 * 64 + mf * 16 + lo;
#pragma unroll
      for (int kk = 0; kk < 2; ++kk)
        a[mf][kk] = *(const bf16x8*)&src[r * 64 + (((kk * 4 + hi) ^ (r & 7)) << 3)];
    }
  };
  auto loadB = [&](bf16x8 (&bq)[2], int buf, int qn) {
    const u16* src = ldsB(buf, qn);
    int r = wn4 * 16 + lo;
#pragma unroll
    for (int kk = 0; kk < 2; ++kk)
      bq[kk] = *(const bf16x8*)&src[r * 64 + (((kk * 4 + hi) ^ (r & 7)) << 3)];
  };

  f32x4 acc00[4] = {}, acc01[4] = {}, acc10[4] = {}, acc11[4] = {};
  bf16x8 a[4][2], b0[2], b1[2];

  auto mma8 = [&](f32x4 (&accq)[4], bf16x8 (&aa)[4][2], bf16x8 (&bb)[2]) {
    __builtin_amdgcn_s_setprio(1);
#pragma unroll
    for (int mf = 0; mf < 4; ++mf)
#pragma unroll
      for (int kk = 0; kk < 2; ++kk)
        accq[mf] = __builtin_amdgcn_mfma_f32_16x16x32_bf16(aa[mf][kk], bb[kk], accq[mf], 0, 0, 0);
    __builtin_amdgcn_s_setprio(0);
  };

  // prologue: tile0 full (6 loads) + tile1 h0 (3 loads); wait tile0 -> 3 outstanding
  stageA(0, 0); stageB(0, 0); stageA(0, 1); stageB(0, 1);
  stageA(1, 0); stageB(1, 0);
  asm volatile("s_waitcnt vmcnt(3)" ::: "memory");
  BAR;

  for (int it = 0; it < niter; ++it) {
    int t0 = 2 * it;
    // PH1
    loadA(a, 0, 0); loadB(b0, 0, 0);
    stageA(t0 + 1, 1);
    FENCE; BAR; WAITL;
    mma8(acc00, a, b0);
    FENCE; BAR;
    // PH2
    loadB(b1, 0, 1);
    stageB(t0 + 1, 1);
    FENCE; BAR; WAITL;
    mma8(acc01, a, b1);
    FENCE; BAR;
    // PH3
    loadA(a, 0, 1);
    stageA(t0 + 2, 0);
    FENCE; BAR; WAITL;
    mma8(acc10, a, b0);
    FENCE; BAR;
    // PH4: gate tile t0+1 complete (3 loads outstanding after)
    stageB(t0 + 2, 0);
    asm volatile("s_waitcnt vmcnt(3)" ::: "memory");
    BAR;
    mma8(acc11, a, b1);
    FENCE; BAR;
    // PH5
    loadA(a, 1, 0); loadB(b0, 1, 0);
    stageA(t0 + 2, 1);
    FENCE; BAR; WAITL;
    mma8(acc00, a, b0);
    FENCE; BAR;
    // PH6
    loadB(b1, 1, 1);
    stageB(t0 + 2, 1);
    FENCE; BAR; WAITL;
    mma8(acc01, a, b1);
    FENCE; BAR;
    // PH7
    loadA(a, 1, 1);
    stageA(t0 + 3, 0);
    FENCE; BAR; WAITL;
    mma8(acc10, a, b0);
    FENCE; BAR;
    // PH8: gate tile t0+2 complete
    stageB(t0 + 3, 0);
    asm volatile("s_waitcnt vmcnt(3)" ::: "memory");
    BAR;
    mma8(acc11, a, b1);
    FENCE; BAR;
  }

  auto epi = [&](f32x4 (&accq)[4], int qm, int qn) {
    int col = n0 + qn * 64 + wn4 * 16 + lo;
    float bb = bias[col];
#pragma unroll
    for (int mf = 0; mf < 4; ++mf) {
      int row = m0 + qm * 128 + wm2 * 64 + mf * 16 + hi * 4;
      const float* rsd = nullptr; int roff = 0;
      if (resid0) { if (row < Msplit) { rsd = resid0; } else { rsd = resid1; roff = Msplit; } }
#pragma unroll
      for (int i = 0; i < 4; ++i) {
        float v = accq[mf][i] + bb;
        if (rsd) v += rsd[(size_t)(row + i - roff) * ldc + col];
        if (OUT_BF16) ((u16*)out)[(size_t)(row + i) * ldc + col] = f2bf(v);
        else          ((float*)out)[(size_t)(row + i) * ldc + col] = v;
      }
    }
  };
  epi(acc00, 0, 0); epi(acc01, 0, 1); epi(acc10, 1, 0); epi(acc11, 1, 1);
}

// ---------------- flash attention: 8 waves x 32q, 32x32x16 MFMA, P in-register ----------------
__global__ __launch_bounds__(512, 2) void k_attn(const u16* __restrict__ qkv,
                                                 const u16* __restrict__ vt01,
                                                 u16* __restrict__ m01) {
  __shared__ __align__(16) u16 q_lds[256 * 64];
  __shared__ __align__(16) u16 k_lds[2][64 * 64];
  __shared__ __align__(16) u16 v_lds[2][64 * 64];
  int z = blockIdx.z;
  const u16* Q  = qkv + (size_t)z * Mc * 2048;
  const u16* Kg = qkv + (size_t)(1 - z) * Mc * 2048;
  const u16* Vt = vt01 + (size_t)(1 - z) * VT_STRIDE;
  u16* Out = m01 + (size_t)z * Mc * Dc;
  int tid = threadIdx.x;
  int w = tid >> 6, l = tid & 63;
  int q31 = l & 31, h = l >> 5;
  int qt = blockIdx.x;
  int bh = blockIdx.y, b = bh >> 4, hd = bh & 15;
  size_t rowQ0 = (size_t)b * Nc + qt * 256;

  {
    int r = tid >> 3, s = tid & 7;
#pragma unroll
    for (int c = 0; c < 4; ++c)
      gl_lds16(Q + (rowQ0 + c * 64 + r) * 2048 + hd * 64 + 8 * (s ^ (r & 7)),
               &q_lds[(size_t)(c * 512 + tid) * 8]);
    gl_lds16(Kg + ((size_t)b * Nc + r) * 2048 + hd * 64 + 8 * (s ^ (r & 7)), &k_lds[0][(size_t)tid * 8]);
    gl_lds16(Vt + ((size_t)bh * 64 + r) * Nc + 8 * (s ^ (r & 7)), &v_lds[0][(size_t)tid * 8]);
  }
  __syncthreads();

  bf16x8 qf[4];
  {
    int row = w * 32 + q31;
#pragma unroll
    for (int dk = 0; dk < 4; ++dk)
      qf[dk] = *(const bf16x8*)&q_lds[row * 64 + (((dk * 2 + h) ^ (row & 7)) << 3)];
  }

  f32x16 o0 = {}, o1 = {};
  float m_ = -INFINITY, ls = 0.f;
  int cur = 0;

  for (int t = 0; t < Nc / 64; ++t) {
    if (t + 1 < Nc / 64) {
      int r = tid >> 3, s = tid & 7;
      gl_lds16(Kg + ((size_t)b * Nc + (t + 1) * 64 + r) * 2048 + hd * 64 + 8 * (s ^ (r & 7)),
               &k_lds[cur ^ 1][(size_t)tid * 8]);
      gl_lds16(Vt + ((size_t)bh * 64 + r) * Nc + (t + 1) * 64 + 8 * (s ^ (r & 7)),
               &v_lds[cur ^ 1][(size_t)tid * 8]);
    }

    f32x16 s0 = {}, s1 = {};
    __builtin_amdgcn_s_setprio(1);
#pragma unroll
    for (int dk = 0; dk < 4; ++dk) {
      int r0 = q31, r1 = 32 + q31;
      bf16x8 k0 = *(const bf16x8*)&k_lds[cur][r0 * 64 + (((dk * 2 + h) ^ (r0 & 7)) << 3)];
      bf16x8 k1 = *(const bf16x8*)&k_lds[cur][r1 * 64 + (((dk * 2 + h) ^ (r1 & 7)) << 3)];
      s0 = __builtin_amdgcn_mfma_f32_32x32x16_bf16(k0, qf[dk], s0, 0, 0, 0);
      s1 = __builtin_amdgcn_mfma_f32_32x32x16_bf16(k1, qf[dk], s1, 0, 0, 0);
    }
    __builtin_amdgcn_s_setprio(0);

    float tm = s0[0];
#pragma unroll
    for (int i = 1; i < 16; ++i) tm = fmaxf(tm, s0[i]);
#pragma unroll
    for (int i = 0; i < 16; ++i) tm = fmaxf(tm, s1[i]);
    tm = fmaxf(tm, __shfl_xor(tm, 32));

    bool defer = __all(tm <= m_ + 8.0f);
    float mn = defer ? m_ : fmaxf(m_, tm);

    float ps = 0.f;
#pragma unroll
    for (int i = 0; i < 16; ++i) { float p = exp2f(s0[i] - mn); s0[i] = p; ps += p; }
#pragma unroll
    for (int i = 0; i < 16; ++i) { float p = exp2f(s1[i] - mn); s1[i] = p; ps += p; }
    ps += __shfl_xor(ps, 32);

    if (defer) {
      ls += ps;
    } else {
      float alpha = exp2f(m_ - mn);
      ls = ls * alpha + ps;
      m_ = mn;
      o0 *= alpha; o1 *= alpha;
    }

    u32 pk0[4][2], pk1[4][2];
#pragma unroll
    for (int a2 = 0; a2 < 4; ++a2)
#pragma unroll
      for (int c2 = 0; c2 < 2; ++c2) {
        asm("v_cvt_pk_bf16_f32 %0, %1, %2" : "=v"(pk0[a2][c2]) : "v"(s0[4 * a2 + 2 * c2]), "v"(s0[4 * a2 + 2 * c2 + 1]));
        asm("v_cvt_pk_bf16_f32 %0, %1, %2" : "=v"(pk1[a2][c2]) : "v"(s1[4 * a2 + 2 * c2]), "v"(s1[4 * a2 + 2 * c2 + 1]));
      }
    bf16x8 pf[4];
#pragma unroll
    for (int ks = 0; ks < 4; ++ks) {
      const int aE = (2 * ks) & 3, aO = (2 * ks + 1) & 3;
      u32 x0, y0, x1, y1;
      if (ks < 2) { x0 = pk0[aE][0]; y0 = pk0[aO][0]; x1 = pk0[aE][1]; y1 = pk0[aO][1]; }
      else        { x0 = pk1[aE][0]; y0 = pk1[aO][0]; x1 = pk1[aE][1]; y1 = pk1[aO][1]; }
      asm("v_permlane32_swap_b32 %0, %1" : "+v"(x0), "+v"(y0));
      asm("v_permlane32_swap_b32 %0, %1" : "+v"(x1), "+v"(y1));
      union { u32 u[4]; bf16x8 v; } fu;
      fu.u[0] = x0; fu.u[1] = x1; fu.u[2] = y0; fu.u[3] = y1;
      pf[ks] = fu.v;
    }

    __builtin_amdgcn_s_setprio(1);
#pragma unroll
    for (int ks = 0; ks < 4; ++ks) {
      int r0 = q31, r1 = 32 + q31;
      bf16x8 v0 = *(const bf16x8*)&v_lds[cur][r0 * 64 + (((ks * 2 + h) ^ (r0 & 7)) << 3)];
      bf16x8 v1 = *(const bf16x8*)&v_lds[cur][r1 * 64 + (((ks * 2 + h) ^ (r1 & 7)) << 3)];
      o0 = __builtin_amdgcn_mfma_f32_32x32x16_bf16(v0, pf[ks], o0, 0, 0, 0);
      o1 = __builtin_amdgcn_mfma_f32_32x32x16_bf16(v1, pf[ks], o1, 0, 0, 0);
    }
    __builtin_amdgcn_s_setprio(0);

    __syncthreads();
    cur ^= 1;
  }

  float inv = 1.f / ls;
  int q_abs = qt * 256 + w * 32 + q31;
  u16* orow = Out + ((size_t)b * Nc + q_abs) * Dc + hd * 64;
#pragma unroll
  for (int rq = 0; rq < 4; ++rq) {
    union { u16 s[4]; uint2 v; } p0, p1;
#pragma unroll
    for (int c = 0; c < 4; ++c) {
      p0.s[c] = f2bf(o0[4 * rq + c] * inv);
      p1.s[c] = f2bf(o1[4 * rq + c] * inv);
    }
    *(uint2*)(orow + 8 * rq + 4 * h) = p0.v;
    *(uint2*)(orow + 32 + 8 * rq + 4 * h) = p1.v;
  }
}

// ---------------- LayerNorm + exact GeLU, in-place on bf16 [rows][2048] ----------------
__global__ __launch_bounds__(256) void k_ln_gelu(u16* __restrict__ hbuf,
                                                 const float* __restrict__ gamma,
                                                 const float* __restrict__ beta) {
  int row = blockIdx.x;
  u16* hp = hbuf + (size_t)row * D2c;
  int tid = threadIdx.x;
  uint4 raw = *(const uint4*)(hp + tid * 8);
  u16* rs = (u16*)&raw;
  float vals[8];
  float s = 0.f, s2 = 0.f;
#pragma unroll
  for (int j = 0; j < 8; ++j) { float v = bf2f(rs[j]); vals[j] = v; s += v; s2 += v * v; }
#pragma unroll
  for (int off = 1; off < 64; off <<= 1) { s += __shfl_xor(s, off); s2 += __shfl_xor(s2, off); }
  __shared__ float red[2][4];
  int w = tid >> 6, l = tid & 63;
  if (l == 0) { red[0][w] = s; red[1][w] = s2; }
  __syncthreads();
  s = red[0][0] + red[0][1] + red[0][2] + red[0][3];
  s2 = red[1][0] + red[1][1] + red[1][2] + red[1][3];
  float mu = s / D2c;
  float var = s2 / D2c - mu * mu;
  float rstd = rsqrtf(var + 1e-5f);
  union { u16 s[8]; uint4 v; } outp;
#pragma unroll
  for (int j = 0; j < 8; ++j) {
    int c = tid * 8 + j;
    float v = (vals[j] - mu) * rstd * gamma[c] + beta[c];
    float g = 0.5f * v * (1.f + erff(v * 0.70710678118654752f));
    outp.s[j] = f2bf(g);
  }
  *(uint4*)(hp + tid * 8) = outp.v;
}

extern "C" void kernel_launch(void* const* d_in, const int* in_sizes, int n_in,
                              void* d_out, int out_size, void* d_ws, size_t ws_size,
                              hipStream_t stream) {
  const float* x0   = (const float*)d_in[0];
  const float* x1   = (const float*)d_in[1];
  const float* Wqk  = (const float*)d_in[2];
  const float* bqk  = (const float*)d_in[3];
  const float* Wv   = (const float*)d_in[4];
  const float* bv   = (const float*)d_in[5];
  const float* Wo   = (const float*)d_in[6];
  const float* bo   = (const float*)d_in[7];
  const float* Wf1  = (const float*)d_in[8];
  const float* bf1  = (const float*)d_in[9];
  const float* gamma= (const float*)d_in[10];
  const float* beta = (const float*)d_in[11];
  const float* Wf2  = (const float*)d_in[12];
  const float* bf2  = (const float*)d_in[13];
  float* y = (float*)d_out;

  char* p = (char*)d_ws;
  auto take = [&](size_t elems) { u16* r = (u16*)p; p += ((elems * 2 + 255) & ~(size_t)255); return r; };
  u16* Wqkvt = take((size_t)2048 * 1024);   // rows 0..1023 = Wqk^T, 1024..2047 = Wv^T
  u16* Wot   = take((size_t)1024 * 1024);
  u16* Wf1t  = take((size_t)2048 * 2048);
  u16* Wf2t  = take((size_t)2048 * 1024);
  u16* x01b  = take((size_t)8192 * 1024);
  u16* qkv   = take((size_t)8192 * 2048);   // later aliased as h01
  u16* vt01  = take(2 * VT_STRIDE);         // later aliased as o01
  u16* m01   = take((size_t)8192 * 1024);
  u16* h01 = qkv;   // FFN1 output (qkv dead after attention)
  u16* o01 = vt01;  // O-proj output (vt dead after attention)

  dim3 blk(256);
  // sqrt(log2(e)/8): applied to both q and k -> S is scaled by log2(e)/8 (exp2-domain softmax)
  const float sq = 0.4246608984f;

  // weight transposes + input converts
  k_transpose_f32_bf16<<<dim3(16, 16), blk, 0, stream>>>(Wqk, Wqkvt, 1024, 1024);
  k_transpose_f32_bf16<<<dim3(16, 16), blk, 0, stream>>>(Wv, Wqkvt + (size_t)1024 * 1024, 1024, 1024);
  k_transpose_f32_bf16<<<dim3(16, 16), blk, 0, stream>>>(Wo, Wot, 1024, 1024);
  k_transpose_f32_bf16<<<dim3(32, 32), blk, 0, stream>>>(Wf1, Wf1t, 2048, 2048);
  k_transpose_f32_bf16<<<dim3(16, 32), blk, 0, stream>>>(Wf2, Wf2t, 2048, 1024);
  k_f32_to_bf16<<<dim3(2048), blk, 0, stream>>>(x0, x01b, 4096 * 1024);
  k_f32_to_bf16<<<dim3(2048), blk, 0, stream>>>(x1, x01b + (size_t)4096 * 1024, 4096 * 1024);

  // fused qk+v projection (8-phase 256^2): [8192,1024] x [1024,2048] -> qkv
  k_gemm8<<<dim3(256), dim3(512), 0, stream>>>(
      x01b, 1024, x01b, 1024, 16, Wqkvt,
      bqk, bv, 1024, sq, 1.f, qkv, 2048, 1024, 8);

  // per-head V transpose (both streams)
  k_v_transpose<<<dim3(16, 64, 2), blk, 0, stream>>>(qkv, vt01);

  // cross attention (both directions in one dispatch)
  k_attn<<<dim3(4, 64, 2), dim3(512), 0, stream>>>(qkv, vt01, m01);

  // output projection (8-phase 256x128): [8192,1024] x [1024,1024] -> o01
  k_gemm8h<true><<<dim3(256), dim3(512), 0, stream>>>(
      m01, 1024, Wot, bo, nullptr, nullptr, 0, o01, 1024, 1024, 8);

  // FFN1 on concat([x, o]) (8-phase 256^2): [8192,2048] x [2048,2048] -> h01
  k_gemm8<<<dim3(256), dim3(512), 0, stream>>>(
      x01b, 1024, o01, 1024, 16, Wf1t,
      bf1, nullptr, 2048, 1.f, 1.f, h01, 2048, 2048, 8);

  // LayerNorm + GeLU in place
  k_ln_gelu<<<dim3(8192), blk, 0, stream>>>(h01, gamma, beta);

  // FFN2 + residual (8-phase 256x128) -> fp32 outputs
  k_gemm8h<false><<<dim3(256), dim3(512), 0, stream>>>(
      h01, 2048, Wf2t, bf2, x0, x1, 4096, y, 1024, 2048, 8);
}